// Round 14
// baseline (295.317 us; speedup 1.0000x reference)
//
#include <hip/hip_runtime.h>

#define BB 8
#define NN 2048
#define DD 256

typedef unsigned short u16;
typedef float f32x4 __attribute__((ext_vector_type(4)));
typedef short s16x8 __attribute__((ext_vector_type(8)));
typedef __bf16 bf16x8 __attribute__((ext_vector_type(8)));
typedef _Float16 f16x8 __attribute__((ext_vector_type(8)));
typedef unsigned short u16x4 __attribute__((ext_vector_type(4)));

#define MFMA_BF(a, b, c)                                                       \
  __builtin_amdgcn_mfma_f32_16x16x32_bf16(__builtin_bit_cast(bf16x8, (a)),     \
                                          __builtin_bit_cast(bf16x8, (b)),     \
                                          (c), 0, 0, 0)
#define MFMA_F16(a, b, c)                                                      \
  __builtin_amdgcn_mfma_f32_16x16x32_f16(__builtin_bit_cast(f16x8, (a)),       \
                                         __builtin_bit_cast(f16x8, (b)),       \
                                         (c), 0, 0, 0)

__device__ inline u16 f2bf(float f) {
  union { float f; unsigned u; } v; v.f = f;
  unsigned r = v.u + 0x7FFFu + ((v.u >> 16) & 1u);
  return (u16)(r >> 16);
}
__device__ inline float bf2f(u16 h) {
  union { unsigned u; float f; } v; v.u = ((unsigned)h) << 16;
  return v.f;
}
__device__ inline u16 f2h(float f) {
  _Float16 h = (_Float16)f;
  return __builtin_bit_cast(unsigned short, h);
}
__device__ inline float h2f(u16 h) {
  _Float16 x = __builtin_bit_cast(_Float16, h);
  return (float)x;
}
struct HL { short h, l; };
__device__ inline HL splitbf(float f) {
  HL r;
  u16 hh = f2bf(f);
  r.h = (short)hh;
  r.l = (short)f2bf(f - bf2f(hh));
  return r;
}
__device__ inline void split8(const f32x4 a, const f32x4 c, s16x8& h, s16x8& lo) {
#pragma unroll
  for (int i = 0; i < 4; ++i) {
    HL r = splitbf(a[i]);
    h[i] = r.h; lo[i] = r.l;
  }
#pragma unroll
  for (int i = 0; i < 4; ++i) {
    HL r = splitbf(c[i]);
    h[4 + i] = r.h; lo[4 + i] = r.l;
  }
}
__device__ inline s16x8 cvt8h(const f32x4 a, const f32x4 c) {
  s16x8 h;
#pragma unroll
  for (int i = 0; i < 4; ++i) h[i] = (short)f2h(a[i]);
#pragma unroll
  for (int i = 0; i < 4; ++i) h[4 + i] = (short)f2h(c[i]);
  return h;
}

// ---------------------------------------------------------------------------
// K0: fused f32 -> fp16 transposes for x1 and x2 (grid z = 16: z<8 -> x1).
// ---------------------------------------------------------------------------
__global__ __launch_bounds__(256) void k_conv2(const float* __restrict__ x1,
                                               const float* __restrict__ x2,
                                               u16* __restrict__ xb1T,
                                               u16* __restrict__ xb2T) {
  __shared__ u16 t[64][68];
  const int zz = blockIdx.z;
  const float* src = (zz < 8) ? x1 : x2;
  u16* dstT = (zz < 8) ? xb1T : xb2T;
  const int b = zz & 7;
  const int n0 = blockIdx.x * 64;
  const int d0 = blockIdx.y * 64;
  const int tid = threadIdx.x;
  const int r = tid >> 4;
  const int c4 = tid & 15;
#pragma unroll
  for (int rr = 0; rr < 4; ++rr) {
    const int row = r + rr * 16;
    const float4 v = *(const float4*)&src[(size_t)(b * NN + n0 + row) * DD + d0 + c4 * 4];
    u16x4 o2 = {f2h(v.x), f2h(v.y), f2h(v.z), f2h(v.w)};
    *(u16x4*)&t[row][c4 * 4] = o2;
  }
  __syncthreads();
  const int d = tid >> 2;
  const int ch = tid & 3;
  u16 buf[16];
#pragma unroll
  for (int j = 0; j < 16; ++j) buf[j] = t[ch * 16 + j][d];
  u16* outp = &dstT[(size_t)(b * DD + d0 + d) * NN + n0 + ch * 16];
  s16x8 v0, v1;
#pragma unroll
  for (int j = 0; j < 8; ++j) { v0[j] = (short)buf[j]; v1[j] = (short)buf[8 + j]; }
  *(s16x8*)outp = v0;
  *(s16x8*)(outp + 8) = v1;
}

// ---------------------------------------------------------------------------
// K1: q = x1 @ W^T + bias via SPLIT-bf16 3-chain (accurate), output fp16.
// ---------------------------------------------------------------------------
__global__ __launch_bounds__(256) void k_qgemm(const float* __restrict__ x1,
                                               const float* __restrict__ W,
                                               const float* __restrict__ bias,
                                               u16* __restrict__ qf) {
  __shared__ char wl[131072];
  const int tid = threadIdx.x;
  const int w = tid >> 6, l = tid & 63, lr = l & 15, lg = l >> 4;
  const int row0 = blockIdx.x * 64 + w * 16;

  s16x8 afh[8], afl[8];
#pragma unroll
  for (int ks = 0; ks < 8; ++ks) {
    const f32x4 a = *(const f32x4*)&x1[(size_t)(row0 + lr) * DD + ks * 32 + lg * 8];
    const f32x4 c = *(const f32x4*)&x1[(size_t)(row0 + lr) * DD + ks * 32 + lg * 8 + 4];
    split8(a, c, afh[ks], afl[ks]);
  }

  const f32x4 zero4 = {0.f, 0.f, 0.f, 0.f};
  f32x4 acc[16];
#pragma unroll
  for (int i = 0; i < 16; ++i) acc[i] = zero4;

  const int er = tid >> 1;
  const int kh = tid & 1;

  for (int eh = 0; eh < 2; ++eh) {
    __syncthreads();
    {
      const int e = eh * 128 + er;
#pragma unroll
      for (int j = 0; j < 16; ++j) {
        const f32x4 a = *(const f32x4*)&W[(size_t)e * DD + kh * 128 + j * 8];
        const f32x4 c = *(const f32x4*)&W[(size_t)e * DD + kh * 128 + j * 8 + 4];
        s16x8 h, lo;
        split8(a, c, h, lo);
        int off = er * 512 + kh * 256 + j * 16;
        off ^= (er & 7) << 4;
        *(s16x8*)(wl + off) = h;
        *(s16x8*)(wl + 65536 + off) = lo;
      }
    }
    __syncthreads();
#pragma unroll
    for (int ct = 0; ct < 8; ++ct) {
      const int el = ct * 16 + lr;
#pragma unroll
      for (int ks = 0; ks < 8; ++ks) {
        int off = el * 512 + ks * 64 + lg * 16;
        off ^= (el & 7) << 4;
        const s16x8 bh = *(const s16x8*)(wl + off);
        const s16x8 bl = *(const s16x8*)(wl + 65536 + off);
        f32x4 acv = acc[eh * 8 + ct];
        acv = MFMA_BF(afh[ks], bh, acv);
        acv = MFMA_BF(afl[ks], bh, acv);
        acv = MFMA_BF(afh[ks], bl, acv);
        acc[eh * 8 + ct] = acv;
      }
    }
  }

#pragma unroll
  for (int i = 0; i < 16; ++i) {
    const int col = (i >> 3) * 128 + (i & 7) * 16 + lr;
    const float bb = bias[col];
#pragma unroll
    for (int r = 0; r < 4; ++r) {
      const int orow = row0 + lg * 4 + r;
      qf[(size_t)orow * DD + col] = f2h(acc[i][r] + bb);
    }
  }
}

// ---------------------------------------------------------------------------
// K2: flash fwd, 512-thr blocks (2/CU = 16 waves/CU). 8 waves = 4 n-waves
// (16 q-rows each) x 2 d-halves (QK+softmax duplicated across the pair; PV
// split). bN+bT double-buffered, one barrier per t. Unnormalized fp16
// partials + (M,L) per row. Grid 512 = (g 0/1 m-halves) x 8b x 32nt.
// ---------------------------------------------------------------------------
__global__ __launch_bounds__(512, 4) void k_flashB(const u16* __restrict__ qf_g,
                                                   const float* __restrict__ x2f,
                                                   const u16* __restrict__ xb2T,
                                                   u16* __restrict__ opart,
                                                   float2* __restrict__ ml) {
  __shared__ char smem[73728];  // bN 2x16K | bT 2x16K | plds 8x1K
  const int tid = threadIdx.x;
  const int w = tid >> 6, l = tid & 63, lr = l & 15, lg = l >> 4;
  const int nw = w >> 1, dh = w & 1;
  const int bid = blockIdx.x;
  const int b = bid & 7, nt = (bid >> 3) & 31, g = bid >> 8;
  const int n0 = nt * 64;

  s16x8 qfr[8];
  {
    const size_t qoff = (size_t)(b * NN + n0 + nw * 16 + lr) * DD;
#pragma unroll
    for (int ks = 0; ks < 8; ++ks)
      qfr[ks] = *(const s16x8*)(qf_g + qoff + ks * 32 + lg * 8);
  }

  const f32x4 zero4 = {0.f, 0.f, 0.f, 0.f};
  f32x4 o[8];
#pragma unroll
  for (int i = 0; i < 8; ++i) o[i] = zero4;
  float M[4] = {-INFINITY, -INFINITY, -INFINITY, -INFINITY};
  float L[4] = {0.f, 0.f, 0.f, 0.f};

  const float* srcF = x2f + (size_t)b * NN * DD;
  const char* srcT = (const char*)(xb2T + (size_t)b * DD * NN);
  char* plds = smem + 65536 + w * 1024;

  // staging: bN by (row, 16-float chunk); bT by (d-row, 32B half)
  const int rN = tid >> 4;   // 0..31
  const int cN = tid & 15;   // 16-float chunk
  const int drT = tid >> 1;  // 0..255
  const int hfT = tid & 1;

  f32x4 ff[4];
  s16x8 stT[2];
  auto LOADS = [&](int m0) {
#pragma unroll
    for (int j = 0; j < 4; ++j)
      ff[j] = *(const f32x4*)&srcF[(size_t)(m0 + rN) * DD + cN * 16 + j * 4];
#pragma unroll
    for (int j = 0; j < 2; ++j)
      stT[j] = *(const s16x8*)(srcT + (size_t)drT * 4096 + (size_t)m0 * 2 + hfT * 32 + j * 16);
  };
  auto WRITES = [&](int buf) {
    char* bN = smem + buf * 16384;
    char* bT = smem + 32768 + buf * 16384;
    const int keyN = (rN & 7) << 4;
    const s16x8 h0 = cvt8h(ff[0], ff[1]);
    const s16x8 h1 = cvt8h(ff[2], ff[3]);
    *(s16x8*)(bN + ((rN * 512 + cN * 32) ^ keyN)) = h0;
    *(s16x8*)(bN + ((rN * 512 + cN * 32 + 16) ^ keyN)) = h1;
    const int keyT = (drT & 7) << 4;
#pragma unroll
    for (int j = 0; j < 2; ++j)
      *(s16x8*)(bT + ((drT * 64 + hfT * 32 + j * 16) ^ keyT)) = stT[j];
  };

  LOADS(g * 1024);
  WRITES(0);
  LOADS(g * 1024 + 32);
  __syncthreads();

  for (int t = 0; t < 32; ++t) {
    const int cur = t & 1;
    if (t < 31) WRITES(cur ^ 1);
    if (t < 30) LOADS(g * 1024 + (t + 2) * 32);
    const char* bN = smem + cur * 16384;
    const char* bT = smem + 32768 + cur * 16384;

    // S = q @ x2^T (full, duplicated across the d-pair)
    f32x4 s0 = zero4, s1 = zero4;
#pragma unroll
    for (int ks = 0; ks < 8; ++ks) {
      int off0 = (lr * 512 + ks * 64 + lg * 16) ^ ((lr & 7) << 4);
      const s16x8 b0 = *(const s16x8*)(bN + off0);
      s0 = MFMA_F16(qfr[ks], b0, s0);
      const int m1 = 16 + lr;
      int off1 = (m1 * 512 + ks * 64 + lg * 16) ^ ((m1 & 7) << 4);
      const s16x8 b1 = *(const s16x8*)(bN + off1);
      s1 = MFMA_F16(qfr[ks], b1, s1);
    }

    // online softmax
    float p0[4], p1[4];
#pragma unroll
    for (int r = 0; r < 4; ++r) {
      float tm = fmaxf(s0[r], s1[r]);
      tm = fmaxf(tm, __shfl_xor(tm, 1));
      tm = fmaxf(tm, __shfl_xor(tm, 2));
      tm = fmaxf(tm, __shfl_xor(tm, 4));
      tm = fmaxf(tm, __shfl_xor(tm, 8));
      const float Mn = fmaxf(M[r], tm);
      const float corr = __expf(M[r] - Mn);
      M[r] = Mn;
      p0[r] = __expf(s0[r] - Mn);
      p1[r] = __expf(s1[r] - Mn);
      L[r] = L[r] * corr + p0[r] + p1[r];
#pragma unroll
      for (int dt = 0; dt < 8; ++dt) o[dt][r] *= corr;
    }

    // P relayout (wave-private, (row&7) swizzle), fp16
#pragma unroll
    for (int r = 0; r < 4; ++r) {
      const int row = lg * 4 + r;
      const int key = (row & 7) << 4;
      int o0 = (row * 64 + lr * 2) ^ key;
      int o1 = (row * 64 + 32 + lr * 2) ^ key;
      *(u16*)(plds + o0) = f2h(p0[r]);
      *(u16*)(plds + o1) = f2h(p1[r]);
    }
    int ra = (lr * 64 + lg * 16) ^ ((lr & 7) << 4);
    const s16x8 pa = *(const s16x8*)(plds + ra);

    // O += P @ x2 over this wave's d-half
#pragma unroll
    for (int dt = 0; dt < 8; ++dt) {
      const int dl = dh * 128 + dt * 16 + lr;
      int off = (dl * 64 + lg * 16) ^ ((dl & 7) << 4);
      const s16x8 bv = *(const s16x8*)(bT + off);
      o[dt] = MFMA_F16(pa, bv, o[dt]);
    }

    __syncthreads();
  }

  // row-sum of L over lr lanes
#pragma unroll
  for (int r = 0; r < 4; ++r) {
    float s = L[r];
    s += __shfl_xor(s, 1); s += __shfl_xor(s, 2);
    s += __shfl_xor(s, 4); s += __shfl_xor(s, 8);
    L[r] = s;
  }

  // partial write: chunk = (g*256 + blin)*8 + w, 2048 u16 per chunk
  const int blin = b * 32 + nt;
  u16* pb = opart + (((size_t)((g * 256 + blin) * 8 + w)) << 11);
#pragma unroll
  for (int dt = 0; dt < 8; ++dt) {
    u16x4 v = {f2h(o[dt][0]), f2h(o[dt][1]), f2h(o[dt][2]), f2h(o[dt][3])};
    *(u16x4*)(pb + ((dt * 64 + l) << 2)) = v;
  }
  if (dh == 0 && lr == 0) {
#pragma unroll
    for (int r = 0; r < 4; ++r) {
      float2 v = {M[r], L[r]};
      ml[g * 16384 + b * 2048 + n0 + nw * 16 + lg * 4 + r] = v;
    }
  }
}

// ---------------------------------------------------------------------------
// K2b: merge flash halves -> out0 + lse.  grid 1024 = 256 blin x 4 nw.
// ---------------------------------------------------------------------------
__global__ __launch_bounds__(256) void k_mergeB(const u16* __restrict__ opart,
                                                const float2* __restrict__ ml,
                                                float* __restrict__ out0,
                                                float* __restrict__ lse) {
  __shared__ float4 cf[16];
  const int bid = blockIdx.x;
  const int blin = bid >> 2, nw = bid & 3;
  const int tid = threadIdx.x;
  const int row0 = (blin >> 5) * 2048 + (blin & 31) * 64 + nw * 16;
  if (tid < 16) {
    const float2 m0 = ml[row0 + tid];
    const float2 m1 = ml[16384 + row0 + tid];
    const float Mf = fmaxf(m0.x, m1.x);
    const float c0 = __expf(m0.x - Mf);
    const float c1 = __expf(m1.x - Mf);
    const float Lf = m0.y * c0 + m1.y * c1;
    float4 v = {c0, c1, 1.f / Lf, 0.f};
    cf[tid] = v;
    lse[row0 + tid] = Mf + __logf(Lf);
  }
  __syncthreads();
  const int lane = tid & 63;
#pragma unroll
  for (int k = 0; k < 4; ++k) {
    const int dd = (tid >> 6) * 4 + k;  // 0..15
    const int dh = dd >> 3, dt = dd & 7;
    const size_t c0b = ((size_t)((0 * 256 + blin) * 8 + nw * 2 + dh)) << 11;
    const size_t c1b = ((size_t)((1 * 256 + blin) * 8 + nw * 2 + dh)) << 11;
    const u16x4 v0 = *(const u16x4*)(opart + c0b + ((dt * 64 + lane) << 2));
    const u16x4 v1 = *(const u16x4*)(opart + c1b + ((dt * 64 + lane) << 2));
#pragma unroll
    for (int r = 0; r < 4; ++r) {
      const int i = (lane >> 4) * 4 + r;
      const float4 c = cf[i];
      out0[(size_t)(row0 + i) * DD + dh * 128 + dt * 16 + (lane & 15)] =
          (h2f((u16)v0[r]) * c.x + h2f((u16)v1[r]) * c.y) * c.z;
    }
  }
}

// ---------------------------------------------------------------------------
// K3: transposed pass, same 512-thr structure (4 m-waves x 2 d-halves).
// ---------------------------------------------------------------------------
__global__ __launch_bounds__(512, 4) void k_passC(const float* __restrict__ x2f,
                                                  const u16* __restrict__ qf_g,
                                                  const u16* __restrict__ xb1T,
                                                  const float* __restrict__ lse,
                                                  u16* __restrict__ opart) {
  __shared__ char smem[73728];
  const int tid = threadIdx.x;
  const int w = tid >> 6, l = tid & 63, lr = l & 15, lg = l >> 4;
  const int nw = w >> 1, dh = w & 1;
  const int bid = blockIdx.x;
  const int b = bid & 7, mt = (bid >> 3) & 31, g = bid >> 8;
  const int m0 = mt * 64;

  s16x8 xf[8];
  {
    const float* xp = x2f + (size_t)(b * NN + m0 + nw * 16 + lr) * DD;
#pragma unroll
    for (int ks = 0; ks < 8; ++ks) {
      const f32x4 a = *(const f32x4*)(xp + ks * 32 + lg * 8);
      const f32x4 c = *(const f32x4*)(xp + ks * 32 + lg * 8 + 4);
      xf[ks] = cvt8h(a, c);
    }
  }

  const f32x4 zero4 = {0.f, 0.f, 0.f, 0.f};
  f32x4 o[8];
#pragma unroll
  for (int i = 0; i < 8; ++i) o[i] = zero4;

  const char* srcQ = (const char*)(qf_g + (size_t)b * NN * DD);
  const char* srcT = (const char*)(xb1T + (size_t)b * DD * NN);
  const float* lsb = lse + (size_t)b * NN;
  char* plds = smem + 65536 + w * 1024;

  const int rN = tid >> 4;   // 0..31 (q rows)
  const int cN = tid & 15;   // 32B chunk
  const int drT = tid >> 1;  // 0..255
  const int hfT = tid & 1;

  s16x8 stQ[2], stT[2];
  auto LOADS = [&](int nn0) {
#pragma unroll
    for (int j = 0; j < 2; ++j) {
      stQ[j] = *(const s16x8*)(srcQ + (size_t)(nn0 + rN) * 512 + cN * 32 + j * 16);
      stT[j] = *(const s16x8*)(srcT + (size_t)drT * 4096 + (size_t)nn0 * 2 + hfT * 32 + j * 16);
    }
  };
  auto WRITES = [&](int buf) {
    char* bQ = smem + buf * 16384;
    char* bT = smem + 32768 + buf * 16384;
    const int keyQ = (rN & 7) << 4;
    const int keyT = (drT & 7) << 4;
#pragma unroll
    for (int j = 0; j < 2; ++j) {
      *(s16x8*)(bQ + ((rN * 512 + cN * 32 + j * 16) ^ keyQ)) = stQ[j];
      *(s16x8*)(bT + ((drT * 64 + hfT * 32 + j * 16) ^ keyT)) = stT[j];
    }
  };

  LOADS(g * 1024);
  WRITES(0);
  LOADS(g * 1024 + 32);
  __syncthreads();

  for (int t = 0; t < 32; ++t) {
    const int cur = t & 1;
    if (t < 31) WRITES(cur ^ 1);
    if (t < 30) LOADS(g * 1024 + (t + 2) * 32);
    const char* bQ = smem + cur * 16384;
    const char* bT = smem + 32768 + cur * 16384;

    // S^T = x2 @ q^T (full, duplicated across the d-pair)
    f32x4 s0 = zero4, s1 = zero4;
#pragma unroll
    for (int ks = 0; ks < 8; ++ks) {
      int off0 = (lr * 512 + ks * 64 + lg * 16) ^ ((lr & 7) << 4);
      const s16x8 b0 = *(const s16x8*)(bQ + off0);
      s0 = MFMA_F16(xf[ks], b0, s0);
      const int n1 = 16 + lr;
      int off1 = (n1 * 512 + ks * 64 + lg * 16) ^ ((n1 & 7) << 4);
      const s16x8 b1 = *(const s16x8*)(bQ + off1);
      s1 = MFMA_F16(xf[ks], b1, s1);
    }

    const int nb = g * 1024 + t * 32;
    const float lv0 = lsb[nb + lr];
    const float lv1 = lsb[nb + 16 + lr];
    float p0[4], p1[4];
#pragma unroll
    for (int r = 0; r < 4; ++r) {
      p0[r] = __expf(s0[r] - lv0);
      p1[r] = __expf(s1[r] - lv1);
    }

#pragma unroll
    for (int r = 0; r < 4; ++r) {
      const int row = lg * 4 + r;
      const int key = (row & 7) << 4;
      int o0 = (row * 64 + lr * 2) ^ key;
      int o1 = (row * 64 + 32 + lr * 2) ^ key;
      *(u16*)(plds + o0) = f2h(p0[r]);
      *(u16*)(plds + o1) = f2h(p1[r]);
    }
    int ra = (lr * 64 + lg * 16) ^ ((lr & 7) << 4);
    const s16x8 pa = *(const s16x8*)(plds + ra);

    // O2 += P^T @ x1 over this wave's d-half
#pragma unroll
    for (int dt = 0; dt < 8; ++dt) {
      const int dl = dh * 128 + dt * 16 + lr;
      int off = (dl * 64 + lg * 16) ^ ((dl & 7) << 4);
      const s16x8 bv = *(const s16x8*)(bT + off);
      o[dt] = MFMA_F16(pa, bv, o[dt]);
    }

    __syncthreads();
  }

  // partial write (additive halves)
  const int blin = b * 32 + mt;
  u16* pb = opart + (((size_t)((g * 256 + blin) * 8 + w)) << 11);
#pragma unroll
  for (int dt = 0; dt < 8; ++dt) {
    u16x4 v = {f2h(o[dt][0]), f2h(o[dt][1]), f2h(o[dt][2]), f2h(o[dt][3])};
    *(u16x4*)(pb + ((dt * 64 + l) << 2)) = v;
  }
}

// ---------------------------------------------------------------------------
// K3b: merge passC halves (pure add) -> out1.
// ---------------------------------------------------------------------------
__global__ __launch_bounds__(256) void k_mergeC(const u16* __restrict__ opart,
                                                float* __restrict__ out1) {
  const int bid = blockIdx.x;
  const int blin = bid >> 2, nw = bid & 3;
  const int tid = threadIdx.x;
  const int row0 = (blin >> 5) * 2048 + (blin & 31) * 64 + nw * 16;
  const int lane = tid & 63;
#pragma unroll
  for (int k = 0; k < 4; ++k) {
    const int dd = (tid >> 6) * 4 + k;
    const int dh = dd >> 3, dt = dd & 7;
    const size_t c0b = ((size_t)((0 * 256 + blin) * 8 + nw * 2 + dh)) << 11;
    const size_t c1b = ((size_t)((1 * 256 + blin) * 8 + nw * 2 + dh)) << 11;
    const u16x4 v0 = *(const u16x4*)(opart + c0b + ((dt * 64 + lane) << 2));
    const u16x4 v1 = *(const u16x4*)(opart + c1b + ((dt * 64 + lane) << 2));
#pragma unroll
    for (int r = 0; r < 4; ++r) {
      const int i = (lane >> 4) * 4 + r;
      out1[(size_t)(row0 + i) * DD + dh * 128 + dt * 16 + (lane & 15)] =
          h2f((u16)v0[r]) + h2f((u16)v1[r]);
    }
  }
}

// ---------------------------------------------------------------------------
extern "C" void kernel_launch(void* const* d_in, const int* in_sizes, int n_in,
                              void* d_out, int out_size, void* d_ws, size_t ws_size,
                              hipStream_t stream) {
  (void)in_sizes; (void)n_in; (void)out_size; (void)ws_size;
  const float* x1 = (const float*)d_in[0];
  const float* x2 = (const float*)d_in[1];
  const float* W  = (const float*)d_in[2];
  const float* bs = (const float*)d_in[3];
  float* out0 = (float*)d_out;
  float* out1 = out0 + (size_t)BB * NN * DD;

  char* ws = (char*)d_ws;
  u16* xb2T  = (u16*)(ws);                  // [B][256][2048] fp16 (8 MB)
  u16* xb1T  = (u16*)(ws + 8388608);        // [B][256][2048] fp16 (8 MB)
  u16* opart = (u16*)(ws + 16777216);       // [2][256][8][2048] fp16 (16 MB)
  // scratch parked in out1's region (all dead before mergeC's full rewrite):
  u16* qf     = (u16*)out1;                         // 8.39 MB
  float2* ml  = (float2*)((char*)out1 + 8388608);   // 256 KB
  float* lseb = (float*)((char*)out1 + 8650752);    // 64 KB

  k_conv2<<<dim3(32, 4, 16), 256, 0, stream>>>(x1, x2, xb1T, xb2T);
  k_qgemm<<<256, 256, 0, stream>>>(x1, W, bs, qf);
  k_flashB<<<512, 512, 0, stream>>>(qf, x2, xb2T, opart, ml);
  k_mergeB<<<1024, 256, 0, stream>>>(opart, ml, out0, lseb);
  k_passC<<<512, 512, 0, stream>>>(x2, qf, xb1T, lseb, opart);
  k_mergeC<<<1024, 256, 0, stream>>>(opart, out1);
}

// Round 15
// 265.701 us; speedup vs baseline: 1.1115x; 1.1115x over previous
//
#include <hip/hip_runtime.h>

#define BB 8
#define NN 2048
#define DD 256

typedef unsigned short u16;
typedef float f32x4 __attribute__((ext_vector_type(4)));
typedef short s16x8 __attribute__((ext_vector_type(8)));
typedef __bf16 bf16x8 __attribute__((ext_vector_type(8)));
typedef _Float16 f16x8 __attribute__((ext_vector_type(8)));
typedef unsigned short u16x4 __attribute__((ext_vector_type(4)));

#define MFMA_BF(a, b, c)                                                       \
  __builtin_amdgcn_mfma_f32_16x16x32_bf16(__builtin_bit_cast(bf16x8, (a)),     \
                                          __builtin_bit_cast(bf16x8, (b)),     \
                                          (c), 0, 0, 0)
#define MFMA_F16(a, b, c)                                                      \
  __builtin_amdgcn_mfma_f32_16x16x32_f16(__builtin_bit_cast(f16x8, (a)),       \
                                         __builtin_bit_cast(f16x8, (b)),       \
                                         (c), 0, 0, 0)

__device__ inline u16 f2bf(float f) {
  union { float f; unsigned u; } v; v.f = f;
  unsigned r = v.u + 0x7FFFu + ((v.u >> 16) & 1u);
  return (u16)(r >> 16);
}
__device__ inline float bf2f(u16 h) {
  union { unsigned u; float f; } v; v.u = ((unsigned)h) << 16;
  return v.f;
}
__device__ inline u16 f2h(float f) {
  _Float16 h = (_Float16)f;
  return __builtin_bit_cast(unsigned short, h);
}
__device__ inline float h2f(u16 h) {
  _Float16 x = __builtin_bit_cast(_Float16, h);
  return (float)x;
}
struct HL { short h, l; };
__device__ inline HL splitbf(float f) {
  HL r;
  u16 hh = f2bf(f);
  r.h = (short)hh;
  r.l = (short)f2bf(f - bf2f(hh));
  return r;
}
__device__ inline void split8(const f32x4 a, const f32x4 c, s16x8& h, s16x8& lo) {
#pragma unroll
  for (int i = 0; i < 4; ++i) {
    HL r = splitbf(a[i]);
    h[i] = r.h; lo[i] = r.l;
  }
#pragma unroll
  for (int i = 0; i < 4; ++i) {
    HL r = splitbf(c[i]);
    h[4 + i] = r.h; lo[4 + i] = r.l;
  }
}
__device__ inline s16x8 cvt8h(const f32x4 a, const f32x4 c) {
  s16x8 h;
#pragma unroll
  for (int i = 0; i < 4; ++i) h[i] = (short)f2h(a[i]);
#pragma unroll
  for (int i = 0; i < 4; ++i) h[4 + i] = (short)f2h(c[i]);
  return h;
}

// ---------------------------------------------------------------------------
// K0: fused f32 -> fp16 transposes for x1 and x2 (grid z = 16: z<8 -> x1).
// ---------------------------------------------------------------------------
__global__ __launch_bounds__(256) void k_conv2(const float* __restrict__ x1,
                                               const float* __restrict__ x2,
                                               u16* __restrict__ xb1T,
                                               u16* __restrict__ xb2T) {
  __shared__ u16 t[64][68];
  const int zz = blockIdx.z;
  const float* src = (zz < 8) ? x1 : x2;
  u16* dstT = (zz < 8) ? xb1T : xb2T;
  const int b = zz & 7;
  const int n0 = blockIdx.x * 64;
  const int d0 = blockIdx.y * 64;
  const int tid = threadIdx.x;
  const int r = tid >> 4;
  const int c4 = tid & 15;
#pragma unroll
  for (int rr = 0; rr < 4; ++rr) {
    const int row = r + rr * 16;
    const float4 v = *(const float4*)&src[(size_t)(b * NN + n0 + row) * DD + d0 + c4 * 4];
    u16x4 o2 = {f2h(v.x), f2h(v.y), f2h(v.z), f2h(v.w)};
    *(u16x4*)&t[row][c4 * 4] = o2;
  }
  __syncthreads();
  const int d = tid >> 2;
  const int ch = tid & 3;
  u16 buf[16];
#pragma unroll
  for (int j = 0; j < 16; ++j) buf[j] = t[ch * 16 + j][d];
  u16* outp = &dstT[(size_t)(b * DD + d0 + d) * NN + n0 + ch * 16];
  s16x8 v0, v1;
#pragma unroll
  for (int j = 0; j < 8; ++j) { v0[j] = (short)buf[j]; v1[j] = (short)buf[8 + j]; }
  *(s16x8*)outp = v0;
  *(s16x8*)(outp + 8) = v1;
}

// ---------------------------------------------------------------------------
// K1: q = x1 @ W^T + bias via SPLIT-bf16 3-chain (accurate), output fp16.
// ---------------------------------------------------------------------------
__global__ __launch_bounds__(256) void k_qgemm(const float* __restrict__ x1,
                                               const float* __restrict__ W,
                                               const float* __restrict__ bias,
                                               u16* __restrict__ qf) {
  __shared__ char wl[131072];
  const int tid = threadIdx.x;
  const int w = tid >> 6, l = tid & 63, lr = l & 15, lg = l >> 4;
  const int row0 = blockIdx.x * 64 + w * 16;

  s16x8 afh[8], afl[8];
#pragma unroll
  for (int ks = 0; ks < 8; ++ks) {
    const f32x4 a = *(const f32x4*)&x1[(size_t)(row0 + lr) * DD + ks * 32 + lg * 8];
    const f32x4 c = *(const f32x4*)&x1[(size_t)(row0 + lr) * DD + ks * 32 + lg * 8 + 4];
    split8(a, c, afh[ks], afl[ks]);
  }

  const f32x4 zero4 = {0.f, 0.f, 0.f, 0.f};
  f32x4 acc[16];
#pragma unroll
  for (int i = 0; i < 16; ++i) acc[i] = zero4;

  const int er = tid >> 1;
  const int kh = tid & 1;

  for (int eh = 0; eh < 2; ++eh) {
    __syncthreads();
    {
      const int e = eh * 128 + er;
#pragma unroll
      for (int j = 0; j < 16; ++j) {
        const f32x4 a = *(const f32x4*)&W[(size_t)e * DD + kh * 128 + j * 8];
        const f32x4 c = *(const f32x4*)&W[(size_t)e * DD + kh * 128 + j * 8 + 4];
        s16x8 h, lo;
        split8(a, c, h, lo);
        int off = er * 512 + kh * 256 + j * 16;
        off ^= (er & 7) << 4;
        *(s16x8*)(wl + off) = h;
        *(s16x8*)(wl + 65536 + off) = lo;
      }
    }
    __syncthreads();
#pragma unroll
    for (int ct = 0; ct < 8; ++ct) {
      const int el = ct * 16 + lr;
#pragma unroll
      for (int ks = 0; ks < 8; ++ks) {
        int off = el * 512 + ks * 64 + lg * 16;
        off ^= (el & 7) << 4;
        const s16x8 bh = *(const s16x8*)(wl + off);
        const s16x8 bl = *(const s16x8*)(wl + 65536 + off);
        f32x4 acv = acc[eh * 8 + ct];
        acv = MFMA_BF(afh[ks], bh, acv);
        acv = MFMA_BF(afl[ks], bh, acv);
        acv = MFMA_BF(afh[ks], bl, acv);
        acc[eh * 8 + ct] = acv;
      }
    }
  }

#pragma unroll
  for (int i = 0; i < 16; ++i) {
    const int col = (i >> 3) * 128 + (i & 7) * 16 + lr;
    const float bb = bias[col];
#pragma unroll
    for (int r = 0; r < 4; ++r) {
      const int orow = row0 + lg * 4 + r;
      qf[(size_t)orow * DD + col] = f2h(acc[i][r] + bb);
    }
  }
}

// ---------------------------------------------------------------------------
// K2: flash fwd, 512-thr blocks. 8 waves = 4 n-waves x 2 d-halves (QK dup,
// PV split). dbuf, one barrier per t. launch_bounds (512,2): LDS (72KB) is
// the occupancy limiter -> 2 blocks/CU iff VGPR<=128, no forced spill.
// ---------------------------------------------------------------------------
__global__ __launch_bounds__(512, 2) void k_flashB(const u16* __restrict__ qf_g,
                                                   const float* __restrict__ x2f,
                                                   const u16* __restrict__ xb2T,
                                                   u16* __restrict__ opart,
                                                   float2* __restrict__ ml) {
  __shared__ char smem[73728];  // bN 2x16K | bT 2x16K | plds 8x1K
  const int tid = threadIdx.x;
  const int w = tid >> 6, l = tid & 63, lr = l & 15, lg = l >> 4;
  const int nw = w >> 1, dh = w & 1;
  const int bid = blockIdx.x;
  const int b = bid & 7, nt = (bid >> 3) & 31, g = bid >> 8;
  const int n0 = nt * 64;

  s16x8 qfr[8];
  {
    const size_t qoff = (size_t)(b * NN + n0 + nw * 16 + lr) * DD;
#pragma unroll
    for (int ks = 0; ks < 8; ++ks)
      qfr[ks] = *(const s16x8*)(qf_g + qoff + ks * 32 + lg * 8);
  }

  const f32x4 zero4 = {0.f, 0.f, 0.f, 0.f};
  f32x4 o[8];
#pragma unroll
  for (int i = 0; i < 8; ++i) o[i] = zero4;
  float M[4] = {-INFINITY, -INFINITY, -INFINITY, -INFINITY};
  float L[4] = {0.f, 0.f, 0.f, 0.f};

  const float* srcF = x2f + (size_t)b * NN * DD;
  const char* srcT = (const char*)(xb2T + (size_t)b * DD * NN);
  char* plds = smem + 65536 + w * 1024;

  const int rN = tid >> 4;   // 0..31
  const int cN = tid & 15;   // 16-float chunk
  const int drT = tid >> 1;  // 0..255
  const int hfT = tid & 1;

  f32x4 ff[4];
  s16x8 stT[2];
  auto LOADS = [&](int m0) {
#pragma unroll
    for (int j = 0; j < 4; ++j)
      ff[j] = *(const f32x4*)&srcF[(size_t)(m0 + rN) * DD + cN * 16 + j * 4];
#pragma unroll
    for (int j = 0; j < 2; ++j)
      stT[j] = *(const s16x8*)(srcT + (size_t)drT * 4096 + (size_t)m0 * 2 + hfT * 32 + j * 16);
  };
  auto WRITES = [&](int buf) {
    char* bN = smem + buf * 16384;
    char* bT = smem + 32768 + buf * 16384;
    const int keyN = (rN & 7) << 4;
    const s16x8 h0 = cvt8h(ff[0], ff[1]);
    const s16x8 h1 = cvt8h(ff[2], ff[3]);
    *(s16x8*)(bN + ((rN * 512 + cN * 32) ^ keyN)) = h0;
    *(s16x8*)(bN + ((rN * 512 + cN * 32 + 16) ^ keyN)) = h1;
    const int keyT = (drT & 7) << 4;
#pragma unroll
    for (int j = 0; j < 2; ++j)
      *(s16x8*)(bT + ((drT * 64 + hfT * 32 + j * 16) ^ keyT)) = stT[j];
  };

  LOADS(g * 1024);
  WRITES(0);
  LOADS(g * 1024 + 32);
  __syncthreads();

  for (int t = 0; t < 32; ++t) {
    const int cur = t & 1;
    if (t < 31) WRITES(cur ^ 1);
    if (t < 30) LOADS(g * 1024 + (t + 2) * 32);
    const char* bN = smem + cur * 16384;
    const char* bT = smem + 32768 + cur * 16384;

    // S = q @ x2^T (full, duplicated across the d-pair)
    f32x4 s0 = zero4, s1 = zero4;
#pragma unroll
    for (int ks = 0; ks < 8; ++ks) {
      int off0 = (lr * 512 + ks * 64 + lg * 16) ^ ((lr & 7) << 4);
      const s16x8 b0 = *(const s16x8*)(bN + off0);
      s0 = MFMA_F16(qfr[ks], b0, s0);
      const int m1 = 16 + lr;
      int off1 = (m1 * 512 + ks * 64 + lg * 16) ^ ((m1 & 7) << 4);
      const s16x8 b1 = *(const s16x8*)(bN + off1);
      s1 = MFMA_F16(qfr[ks], b1, s1);
    }

    // online softmax
    float p0[4], p1[4];
#pragma unroll
    for (int r = 0; r < 4; ++r) {
      float tm = fmaxf(s0[r], s1[r]);
      tm = fmaxf(tm, __shfl_xor(tm, 1));
      tm = fmaxf(tm, __shfl_xor(tm, 2));
      tm = fmaxf(tm, __shfl_xor(tm, 4));
      tm = fmaxf(tm, __shfl_xor(tm, 8));
      const float Mn = fmaxf(M[r], tm);
      const float corr = __expf(M[r] - Mn);
      M[r] = Mn;
      p0[r] = __expf(s0[r] - Mn);
      p1[r] = __expf(s1[r] - Mn);
      L[r] = L[r] * corr + p0[r] + p1[r];
#pragma unroll
      for (int dt = 0; dt < 8; ++dt) o[dt][r] *= corr;
    }

    // P relayout (wave-private, (row&7) swizzle), fp16
#pragma unroll
    for (int r = 0; r < 4; ++r) {
      const int row = lg * 4 + r;
      const int key = (row & 7) << 4;
      int o0 = (row * 64 + lr * 2) ^ key;
      int o1 = (row * 64 + 32 + lr * 2) ^ key;
      *(u16*)(plds + o0) = f2h(p0[r]);
      *(u16*)(plds + o1) = f2h(p1[r]);
    }
    int ra = (lr * 64 + lg * 16) ^ ((lr & 7) << 4);
    const s16x8 pa = *(const s16x8*)(plds + ra);

    // O += P @ x2 over this wave's d-half
#pragma unroll
    for (int dt = 0; dt < 8; ++dt) {
      const int dl = dh * 128 + dt * 16 + lr;
      int off = (dl * 64 + lg * 16) ^ ((dl & 7) << 4);
      const s16x8 bv = *(const s16x8*)(bT + off);
      o[dt] = MFMA_F16(pa, bv, o[dt]);
    }

    __syncthreads();
  }

  // row-sum of L over lr lanes
#pragma unroll
  for (int r = 0; r < 4; ++r) {
    float s = L[r];
    s += __shfl_xor(s, 1); s += __shfl_xor(s, 2);
    s += __shfl_xor(s, 4); s += __shfl_xor(s, 8);
    L[r] = s;
  }

  // partial write: chunk = (g*256 + blin)*8 + w, 2048 u16 per chunk
  const int blin = b * 32 + nt;
  u16* pb = opart + (((size_t)((g * 256 + blin) * 8 + w)) << 11);
#pragma unroll
  for (int dt = 0; dt < 8; ++dt) {
    u16x4 v = {f2h(o[dt][0]), f2h(o[dt][1]), f2h(o[dt][2]), f2h(o[dt][3])};
    *(u16x4*)(pb + ((dt * 64 + l) << 2)) = v;
  }
  if (dh == 0 && lr == 0) {
#pragma unroll
    for (int r = 0; r < 4; ++r) {
      float2 v = {M[r], L[r]};
      ml[g * 16384 + b * 2048 + n0 + nw * 16 + lg * 4 + r] = v;
    }
  }
}

// ---------------------------------------------------------------------------
// K2b: merge flash halves -> out0 + lse.  grid 1024 = 256 blin x 4 nw.
// ---------------------------------------------------------------------------
__global__ __launch_bounds__(256) void k_mergeB(const u16* __restrict__ opart,
                                                const float2* __restrict__ ml,
                                                float* __restrict__ out0,
                                                float* __restrict__ lse) {
  __shared__ float4 cf[16];
  const int bid = blockIdx.x;
  const int blin = bid >> 2, nw = bid & 3;
  const int tid = threadIdx.x;
  const int row0 = (blin >> 5) * 2048 + (blin & 31) * 64 + nw * 16;
  if (tid < 16) {
    const float2 m0 = ml[row0 + tid];
    const float2 m1 = ml[16384 + row0 + tid];
    const float Mf = fmaxf(m0.x, m1.x);
    const float c0 = __expf(m0.x - Mf);
    const float c1 = __expf(m1.x - Mf);
    const float Lf = m0.y * c0 + m1.y * c1;
    float4 v = {c0, c1, 1.f / Lf, 0.f};
    cf[tid] = v;
    lse[row0 + tid] = Mf + __logf(Lf);
  }
  __syncthreads();
  const int lane = tid & 63;
#pragma unroll
  for (int k = 0; k < 4; ++k) {
    const int dd = (tid >> 6) * 4 + k;  // 0..15
    const int dh = dd >> 3, dt = dd & 7;
    const size_t c0b = ((size_t)((0 * 256 + blin) * 8 + nw * 2 + dh)) << 11;
    const size_t c1b = ((size_t)((1 * 256 + blin) * 8 + nw * 2 + dh)) << 11;
    const u16x4 v0 = *(const u16x4*)(opart + c0b + ((dt * 64 + lane) << 2));
    const u16x4 v1 = *(const u16x4*)(opart + c1b + ((dt * 64 + lane) << 2));
#pragma unroll
    for (int r = 0; r < 4; ++r) {
      const int i = (lane >> 4) * 4 + r;
      const float4 c = cf[i];
      out0[(size_t)(row0 + i) * DD + dh * 128 + dt * 16 + (lane & 15)] =
          (h2f((u16)v0[r]) * c.x + h2f((u16)v1[r]) * c.y) * c.z;
    }
  }
}

// ---------------------------------------------------------------------------
// K3: transposed pass, same 512-thr structure (4 m-waves x 2 d-halves).
// ---------------------------------------------------------------------------
__global__ __launch_bounds__(512, 2) void k_passC(const float* __restrict__ x2f,
                                                  const u16* __restrict__ qf_g,
                                                  const u16* __restrict__ xb1T,
                                                  const float* __restrict__ lse,
                                                  u16* __restrict__ opart) {
  __shared__ char smem[73728];
  const int tid = threadIdx.x;
  const int w = tid >> 6, l = tid & 63, lr = l & 15, lg = l >> 4;
  const int nw = w >> 1, dh = w & 1;
  const int bid = blockIdx.x;
  const int b = bid & 7, mt = (bid >> 3) & 31, g = bid >> 8;
  const int m0 = mt * 64;

  s16x8 xf[8];
  {
    const float* xp = x2f + (size_t)(b * NN + m0 + nw * 16 + lr) * DD;
#pragma unroll
    for (int ks = 0; ks < 8; ++ks) {
      const f32x4 a = *(const f32x4*)(xp + ks * 32 + lg * 8);
      const f32x4 c = *(const f32x4*)(xp + ks * 32 + lg * 8 + 4);
      xf[ks] = cvt8h(a, c);
    }
  }

  const f32x4 zero4 = {0.f, 0.f, 0.f, 0.f};
  f32x4 o[8];
#pragma unroll
  for (int i = 0; i < 8; ++i) o[i] = zero4;

  const char* srcQ = (const char*)(qf_g + (size_t)b * NN * DD);
  const char* srcT = (const char*)(xb1T + (size_t)b * DD * NN);
  const float* lsb = lse + (size_t)b * NN;
  char* plds = smem + 65536 + w * 1024;

  const int rN = tid >> 4;   // 0..31 (q rows)
  const int cN = tid & 15;   // 32B chunk
  const int drT = tid >> 1;  // 0..255
  const int hfT = tid & 1;

  s16x8 stQ[2], stT[2];
  auto LOADS = [&](int nn0) {
#pragma unroll
    for (int j = 0; j < 2; ++j) {
      stQ[j] = *(const s16x8*)(srcQ + (size_t)(nn0 + rN) * 512 + cN * 32 + j * 16);
      stT[j] = *(const s16x8*)(srcT + (size_t)drT * 4096 + (size_t)nn0 * 2 + hfT * 32 + j * 16);
    }
  };
  auto WRITES = [&](int buf) {
    char* bQ = smem + buf * 16384;
    char* bT = smem + 32768 + buf * 16384;
    const int keyQ = (rN & 7) << 4;
    const int keyT = (drT & 7) << 4;
#pragma unroll
    for (int j = 0; j < 2; ++j) {
      *(s16x8*)(bQ + ((rN * 512 + cN * 32 + j * 16) ^ keyQ)) = stQ[j];
      *(s16x8*)(bT + ((drT * 64 + hfT * 32 + j * 16) ^ keyT)) = stT[j];
    }
  };

  LOADS(g * 1024);
  WRITES(0);
  LOADS(g * 1024 + 32);
  __syncthreads();

  for (int t = 0; t < 32; ++t) {
    const int cur = t & 1;
    if (t < 31) WRITES(cur ^ 1);
    if (t < 30) LOADS(g * 1024 + (t + 2) * 32);
    const char* bQ = smem + cur * 16384;
    const char* bT = smem + 32768 + cur * 16384;

    // S^T = x2 @ q^T (full, duplicated across the d-pair)
    f32x4 s0 = zero4, s1 = zero4;
#pragma unroll
    for (int ks = 0; ks < 8; ++ks) {
      int off0 = (lr * 512 + ks * 64 + lg * 16) ^ ((lr & 7) << 4);
      const s16x8 b0 = *(const s16x8*)(bQ + off0);
      s0 = MFMA_F16(xf[ks], b0, s0);
      const int n1 = 16 + lr;
      int off1 = (n1 * 512 + ks * 64 + lg * 16) ^ ((n1 & 7) << 4);
      const s16x8 b1 = *(const s16x8*)(bQ + off1);
      s1 = MFMA_F16(xf[ks], b1, s1);
    }

    const int nb = g * 1024 + t * 32;
    const float lv0 = lsb[nb + lr];
    const float lv1 = lsb[nb + 16 + lr];
    float p0[4], p1[4];
#pragma unroll
    for (int r = 0; r < 4; ++r) {
      p0[r] = __expf(s0[r] - lv0);
      p1[r] = __expf(s1[r] - lv1);
    }

#pragma unroll
    for (int r = 0; r < 4; ++r) {
      const int row = lg * 4 + r;
      const int key = (row & 7) << 4;
      int o0 = (row * 64 + lr * 2) ^ key;
      int o1 = (row * 64 + 32 + lr * 2) ^ key;
      *(u16*)(plds + o0) = f2h(p0[r]);
      *(u16*)(plds + o1) = f2h(p1[r]);
    }
    int ra = (lr * 64 + lg * 16) ^ ((lr & 7) << 4);
    const s16x8 pa = *(const s16x8*)(plds + ra);

    // O2 += P^T @ x1 over this wave's d-half
#pragma unroll
    for (int dt = 0; dt < 8; ++dt) {
      const int dl = dh * 128 + dt * 16 + lr;
      int off = (dl * 64 + lg * 16) ^ ((dl & 7) << 4);
      const s16x8 bv = *(const s16x8*)(bT + off);
      o[dt] = MFMA_F16(pa, bv, o[dt]);
    }

    __syncthreads();
  }

  // partial write (additive halves)
  const int blin = b * 32 + mt;
  u16* pb = opart + (((size_t)((g * 256 + blin) * 8 + w)) << 11);
#pragma unroll
  for (int dt = 0; dt < 8; ++dt) {
    u16x4 v = {f2h(o[dt][0]), f2h(o[dt][1]), f2h(o[dt][2]), f2h(o[dt][3])};
    *(u16x4*)(pb + ((dt * 64 + l) << 2)) = v;
  }
}

// ---------------------------------------------------------------------------
// K3b: merge passC halves (pure add) -> out1.
// ---------------------------------------------------------------------------
__global__ __launch_bounds__(256) void k_mergeC(const u16* __restrict__ opart,
                                                float* __restrict__ out1) {
  const int bid = blockIdx.x;
  const int blin = bid >> 2, nw = bid & 3;
  const int tid = threadIdx.x;
  const int row0 = (blin >> 5) * 2048 + (blin & 31) * 64 + nw * 16;
  const int lane = tid & 63;
#pragma unroll
  for (int k = 0; k < 4; ++k) {
    const int dd = (tid >> 6) * 4 + k;
    const int dh = dd >> 3, dt = dd & 7;
    const size_t c0b = ((size_t)((0 * 256 + blin) * 8 + nw * 2 + dh)) << 11;
    const size_t c1b = ((size_t)((1 * 256 + blin) * 8 + nw * 2 + dh)) << 11;
    const u16x4 v0 = *(const u16x4*)(opart + c0b + ((dt * 64 + lane) << 2));
    const u16x4 v1 = *(const u16x4*)(opart + c1b + ((dt * 64 + lane) << 2));
#pragma unroll
    for (int r = 0; r < 4; ++r) {
      const int i = (lane >> 4) * 4 + r;
      out1[(size_t)(row0 + i) * DD + dh * 128 + dt * 16 + (lane & 15)] =
          h2f((u16)v0[r]) + h2f((u16)v1[r]);
    }
  }
}

// ---------------------------------------------------------------------------
extern "C" void kernel_launch(void* const* d_in, const int* in_sizes, int n_in,
                              void* d_out, int out_size, void* d_ws, size_t ws_size,
                              hipStream_t stream) {
  (void)in_sizes; (void)n_in; (void)out_size; (void)ws_size;
  const float* x1 = (const float*)d_in[0];
  const float* x2 = (const float*)d_in[1];
  const float* W  = (const float*)d_in[2];
  const float* bs = (const float*)d_in[3];
  float* out0 = (float*)d_out;
  float* out1 = out0 + (size_t)BB * NN * DD;

  char* ws = (char*)d_ws;
  u16* xb2T  = (u16*)(ws);                  // [B][256][2048] fp16 (8 MB)
  u16* xb1T  = (u16*)(ws + 8388608);        // [B][256][2048] fp16 (8 MB)
  u16* opart = (u16*)(ws + 16777216);       // [2][256][8][2048] fp16 (16 MB)
  // scratch parked in out1's region (all dead before mergeC's full rewrite):
  u16* qf     = (u16*)out1;                         // 8.39 MB
  float2* ml  = (float2*)((char*)out1 + 8388608);   // 256 KB
  float* lseb = (float*)((char*)out1 + 8650752);    // 64 KB

  k_conv2<<<dim3(32, 4, 16), 256, 0, stream>>>(x1, x2, xb1T, xb2T);
  k_qgemm<<<256, 256, 0, stream>>>(x1, W, bs, qf);
  k_flashB<<<512, 512, 0, stream>>>(qf, x2, xb2T, opart, ml);
  k_mergeB<<<1024, 256, 0, stream>>>(opart, ml, out0, lseb);
  k_passC<<<512, 512, 0, stream>>>(x2, qf, xb1T, lseb, opart);
  k_mergeC<<<1024, 256, 0, stream>>>(opart, out1);
}

// Round 17
// 246.245 us; speedup vs baseline: 1.1993x; 1.0790x over previous
//
#include <hip/hip_runtime.h>

#define BB 8
#define NN 2048
#define DD 256

typedef unsigned short u16;
typedef float f32x4 __attribute__((ext_vector_type(4)));
typedef short s16x8 __attribute__((ext_vector_type(8)));
typedef __bf16 bf16x8 __attribute__((ext_vector_type(8)));
typedef _Float16 f16x8 __attribute__((ext_vector_type(8)));
typedef unsigned short u16x4 __attribute__((ext_vector_type(4)));

#define MFMA_BF(a, b, c)                                                       \
  __builtin_amdgcn_mfma_f32_16x16x32_bf16(__builtin_bit_cast(bf16x8, (a)),     \
                                          __builtin_bit_cast(bf16x8, (b)),     \
                                          (c), 0, 0, 0)
#define MFMA_F16(a, b, c)                                                      \
  __builtin_amdgcn_mfma_f32_16x16x32_f16(__builtin_bit_cast(f16x8, (a)),       \
                                         __builtin_bit_cast(f16x8, (b)),       \
                                         (c), 0, 0, 0)

__device__ inline u16 f2bf(float f) {
  union { float f; unsigned u; } v; v.f = f;
  unsigned r = v.u + 0x7FFFu + ((v.u >> 16) & 1u);
  return (u16)(r >> 16);
}
__device__ inline float bf2f(u16 h) {
  union { unsigned u; float f; } v; v.u = ((unsigned)h) << 16;
  return v.f;
}
__device__ inline u16 f2h(float f) {
  _Float16 h = (_Float16)f;
  return __builtin_bit_cast(unsigned short, h);
}
__device__ inline float h2f(u16 h) {
  _Float16 x = __builtin_bit_cast(_Float16, h);
  return (float)x;
}
struct HL { short h, l; };
__device__ inline HL splitbf(float f) {
  HL r;
  u16 hh = f2bf(f);
  r.h = (short)hh;
  r.l = (short)f2bf(f - bf2f(hh));
  return r;
}
__device__ inline void split8(const f32x4 a, const f32x4 c, s16x8& h, s16x8& lo) {
#pragma unroll
  for (int i = 0; i < 4; ++i) {
    HL r = splitbf(a[i]);
    h[i] = r.h; lo[i] = r.l;
  }
#pragma unroll
  for (int i = 0; i < 4; ++i) {
    HL r = splitbf(c[i]);
    h[4 + i] = r.h; lo[4 + i] = r.l;
  }
}
__device__ inline s16x8 cvt8h(const f32x4 a, const f32x4 c) {
  s16x8 h;
#pragma unroll
  for (int i = 0; i < 4; ++i) h[i] = (short)f2h(a[i]);
#pragma unroll
  for (int i = 0; i < 4; ++i) h[4 + i] = (short)f2h(c[i]);
  return h;
}

// async global->LDS, 16B/lane; LDS dest = wave-uniform base + lane*16.
__device__ inline void gll16(const void* g, void* l) {
  __builtin_amdgcn_global_load_lds(
      (const __attribute__((address_space(1))) unsigned int*)g,
      (__attribute__((address_space(3))) unsigned int*)l, 16, 0, 0);
}

// ---------------------------------------------------------------------------
// K0: f32 -> fp16 transposes for x1/x2; x2 also gets a row-major fp16 copy.
// ---------------------------------------------------------------------------
__global__ __launch_bounds__(256) void k_conv2(const float* __restrict__ x1,
                                               const float* __restrict__ x2,
                                               u16* __restrict__ xb1T,
                                               u16* __restrict__ xb2T,
                                               u16* __restrict__ xb2n) {
  __shared__ u16 t[64][68];
  const int zz = blockIdx.z;
  const float* src = (zz < 8) ? x1 : x2;
  u16* dstT = (zz < 8) ? xb1T : xb2T;
  u16* dstN = (zz < 8) ? (u16*)0 : xb2n;
  const int b = zz & 7;
  const int n0 = blockIdx.x * 64;
  const int d0 = blockIdx.y * 64;
  const int tid = threadIdx.x;
  const int r = tid >> 4;
  const int c4 = tid & 15;
#pragma unroll
  for (int rr = 0; rr < 4; ++rr) {
    const int row = r + rr * 16;
    const float4 v = *(const float4*)&src[(size_t)(b * NN + n0 + row) * DD + d0 + c4 * 4];
    u16x4 o2 = {f2h(v.x), f2h(v.y), f2h(v.z), f2h(v.w)};
    if (dstN)
      *(u16x4*)&dstN[(size_t)(b * NN + n0 + row) * DD + d0 + c4 * 4] = o2;
    *(u16x4*)&t[row][c4 * 4] = o2;
  }
  __syncthreads();
  const int d = tid >> 2;
  const int ch = tid & 3;
  u16 buf[16];
#pragma unroll
  for (int j = 0; j < 16; ++j) buf[j] = t[ch * 16 + j][d];
  u16* outp = &dstT[(size_t)(b * DD + d0 + d) * NN + n0 + ch * 16];
  s16x8 v0, v1;
#pragma unroll
  for (int j = 0; j < 8; ++j) { v0[j] = (short)buf[j]; v1[j] = (short)buf[8 + j]; }
  *(s16x8*)outp = v0;
  *(s16x8*)(outp + 8) = v1;
}

// ---------------------------------------------------------------------------
// K1: q = x1 @ W^T + bias via SPLIT-bf16 3-chain (accurate), output fp16.
// ---------------------------------------------------------------------------
__global__ __launch_bounds__(256) void k_qgemm(const float* __restrict__ x1,
                                               const float* __restrict__ W,
                                               const float* __restrict__ bias,
                                               u16* __restrict__ qf) {
  __shared__ char wl[131072];
  const int tid = threadIdx.x;
  const int w = tid >> 6, l = tid & 63, lr = l & 15, lg = l >> 4;
  const int row0 = blockIdx.x * 64 + w * 16;

  s16x8 afh[8], afl[8];
#pragma unroll
  for (int ks = 0; ks < 8; ++ks) {
    const f32x4 a = *(const f32x4*)&x1[(size_t)(row0 + lr) * DD + ks * 32 + lg * 8];
    const f32x4 c = *(const f32x4*)&x1[(size_t)(row0 + lr) * DD + ks * 32 + lg * 8 + 4];
    split8(a, c, afh[ks], afl[ks]);
  }

  const f32x4 zero4 = {0.f, 0.f, 0.f, 0.f};
  f32x4 acc[16];
#pragma unroll
  for (int i = 0; i < 16; ++i) acc[i] = zero4;

  const int er = tid >> 1;
  const int kh = tid & 1;

  for (int eh = 0; eh < 2; ++eh) {
    __syncthreads();
    {
      const int e = eh * 128 + er;
#pragma unroll
      for (int j = 0; j < 16; ++j) {
        const f32x4 a = *(const f32x4*)&W[(size_t)e * DD + kh * 128 + j * 8];
        const f32x4 c = *(const f32x4*)&W[(size_t)e * DD + kh * 128 + j * 8 + 4];
        s16x8 h, lo;
        split8(a, c, h, lo);
        int off = er * 512 + kh * 256 + j * 16;
        off ^= (er & 7) << 4;
        *(s16x8*)(wl + off) = h;
        *(s16x8*)(wl + 65536 + off) = lo;
      }
    }
    __syncthreads();
#pragma unroll
    for (int ct = 0; ct < 8; ++ct) {
      const int el = ct * 16 + lr;
#pragma unroll
      for (int ks = 0; ks < 8; ++ks) {
        int off = el * 512 + ks * 64 + lg * 16;
        off ^= (el & 7) << 4;
        const s16x8 bh = *(const s16x8*)(wl + off);
        const s16x8 bl = *(const s16x8*)(wl + 65536 + off);
        f32x4 acv = acc[eh * 8 + ct];
        acv = MFMA_BF(afh[ks], bh, acv);
        acv = MFMA_BF(afl[ks], bh, acv);
        acv = MFMA_BF(afh[ks], bl, acv);
        acc[eh * 8 + ct] = acv;
      }
    }
  }

#pragma unroll
  for (int i = 0; i < 16; ++i) {
    const int col = (i >> 3) * 128 + (i & 7) * 16 + lr;
    const float bb = bias[col];
#pragma unroll
    for (int r = 0; r < 4; ++r) {
      const int orow = row0 + lg * 4 + r;
      qf[(size_t)orow * DD + col] = f2h(acc[i][r] + bb);
    }
  }
}

// ---------------------------------------------------------------------------
// K2: flash fwd, 512-thr blocks, 8 waves = 4 n-waves x 2 d-halves.
// gll staging; bN swizzle is a within-row involution (src = idx^key).
// bT swizzle crosses rows -> source uses the TRUE INVERSE:
//   d_a = (idx>>6) ^ ((idx>>8)&1); src = idx ^ ((d_a&7)<<4).
// ---------------------------------------------------------------------------
__global__ __launch_bounds__(512, 2) void k_flashB(const u16* __restrict__ qf_g,
                                                   const u16* __restrict__ xb2n,
                                                   const u16* __restrict__ xb2T,
                                                   u16* __restrict__ opart,
                                                   float2* __restrict__ ml) {
  __shared__ char smem[73728];  // bN 2x16K | bT 2x16K | plds 8x1K
  const int tid = threadIdx.x;
  const int w = tid >> 6, l = tid & 63, lr = l & 15, lg = l >> 4;
  const int nw = w >> 1, dh = w & 1;
  const int bid = blockIdx.x;
  const int b = bid & 7, nt = (bid >> 3) & 31, g = bid >> 8;
  const int n0 = nt * 64;

  s16x8 qfr[8];
  {
    const size_t qoff = (size_t)(b * NN + n0 + nw * 16 + lr) * DD;
#pragma unroll
    for (int ks = 0; ks < 8; ++ks)
      qfr[ks] = *(const s16x8*)(qf_g + qoff + ks * 32 + lg * 8);
  }

  const f32x4 zero4 = {0.f, 0.f, 0.f, 0.f};
  f32x4 o[8];
#pragma unroll
  for (int i = 0; i < 8; ++i) o[i] = zero4;
  float M[4] = {-INFINITY, -INFINITY, -INFINITY, -INFINITY};
  float L[4] = {0.f, 0.f, 0.f, 0.f};

  const u16* xnb = xb2n + (size_t)b * NN * DD;
  const u16* xtb = xb2T + (size_t)b * DD * NN;
  char* plds = smem + 65536 + w * 1024;

  // per-lane gll source addressing (loop-invariant)
  const int idx0 = w * 2048 + l * 16;
  const int idx1 = idx0 + 1024;
  // bN (within-row involution)
  const int rowN0 = idx0 >> 9, cbN0 = (idx0 & 511) ^ ((rowN0 & 7) << 4);
  const int rowN1 = idx1 >> 9, cbN1 = (idx1 & 511) ^ ((rowN1 & 7) << 4);
  // bT (row-crossing bijection -> inverse map)
  const int da0 = (idx0 >> 6) ^ ((idx0 >> 8) & 1);
  const int sA0 = idx0 ^ ((da0 & 7) << 4);
  const int tRow0 = sA0 >> 6, tCol0 = (sA0 & 63) >> 1;
  const int da1 = (idx1 >> 6) ^ ((idx1 >> 8) & 1);
  const int sA1 = idx1 ^ ((da1 & 7) << 4);
  const int tRow1 = sA1 >> 6, tCol1 = (sA1 & 63) >> 1;

  auto ISSUE = [&](int buf, int m0) {
    char* bN = smem + buf * 16384;
    char* bT = smem + 32768 + buf * 16384;
    gll16(xnb + (size_t)(m0 + rowN0) * DD + (cbN0 >> 1), bN + w * 2048);
    gll16(xnb + (size_t)(m0 + rowN1) * DD + (cbN1 >> 1), bN + w * 2048 + 1024);
    gll16(xtb + (size_t)tRow0 * NN + m0 + tCol0, bT + w * 2048);
    gll16(xtb + (size_t)tRow1 * NN + m0 + tCol1, bT + w * 2048 + 1024);
  };

  ISSUE(0, g * 1024);
  __syncthreads();

  for (int t = 0; t < 32; ++t) {
    const int cur = t & 1;
    if (t < 31) ISSUE(cur ^ 1, g * 1024 + (t + 1) * 32);
    const char* bN = smem + cur * 16384;
    const char* bT = smem + 32768 + cur * 16384;

    // S = q @ x2^T (full, duplicated across the d-pair)
    f32x4 s0 = zero4, s1 = zero4;
#pragma unroll
    for (int ks = 0; ks < 8; ++ks) {
      int off0 = (lr * 512 + ks * 64 + lg * 16) ^ ((lr & 7) << 4);
      const s16x8 b0 = *(const s16x8*)(bN + off0);
      s0 = MFMA_F16(qfr[ks], b0, s0);
      const int m1 = 16 + lr;
      int off1 = (m1 * 512 + ks * 64 + lg * 16) ^ ((m1 & 7) << 4);
      const s16x8 b1 = *(const s16x8*)(bN + off1);
      s1 = MFMA_F16(qfr[ks], b1, s1);
    }

    // online softmax
    float p0[4], p1[4];
#pragma unroll
    for (int r = 0; r < 4; ++r) {
      float tm = fmaxf(s0[r], s1[r]);
      tm = fmaxf(tm, __shfl_xor(tm, 1));
      tm = fmaxf(tm, __shfl_xor(tm, 2));
      tm = fmaxf(tm, __shfl_xor(tm, 4));
      tm = fmaxf(tm, __shfl_xor(tm, 8));
      const float Mn = fmaxf(M[r], tm);
      const float corr = __expf(M[r] - Mn);
      M[r] = Mn;
      p0[r] = __expf(s0[r] - Mn);
      p1[r] = __expf(s1[r] - Mn);
      L[r] = L[r] * corr + p0[r] + p1[r];
#pragma unroll
      for (int dt = 0; dt < 8; ++dt) o[dt][r] *= corr;
    }

    // P relayout (wave-private, (row&7) swizzle), fp16
#pragma unroll
    for (int r = 0; r < 4; ++r) {
      const int row = lg * 4 + r;
      const int key = (row & 7) << 4;
      int o0 = (row * 64 + lr * 2) ^ key;
      int o1 = (row * 64 + 32 + lr * 2) ^ key;
      *(u16*)(plds + o0) = f2h(p0[r]);
      *(u16*)(plds + o1) = f2h(p1[r]);
    }
    int ra = (lr * 64 + lg * 16) ^ ((lr & 7) << 4);
    const s16x8 pa = *(const s16x8*)(plds + ra);

    // O += P @ x2 over this wave's d-half
#pragma unroll
    for (int dt = 0; dt < 8; ++dt) {
      const int dl = dh * 128 + dt * 16 + lr;
      int off = (dl * 64 + lg * 16) ^ ((dl & 7) << 4);
      const s16x8 bv = *(const s16x8*)(bT + off);
      o[dt] = MFMA_F16(pa, bv, o[dt]);
    }

    __syncthreads();  // drains gll into next buf + publishes read-done
  }

  // row-sum of L over lr lanes
#pragma unroll
  for (int r = 0; r < 4; ++r) {
    float s = L[r];
    s += __shfl_xor(s, 1); s += __shfl_xor(s, 2);
    s += __shfl_xor(s, 4); s += __shfl_xor(s, 8);
    L[r] = s;
  }

  // partial write: chunk = (g*256 + blin)*8 + w, 2048 u16 per chunk
  const int blin = b * 32 + nt;
  u16* pb = opart + (((size_t)((g * 256 + blin) * 8 + w)) << 11);
#pragma unroll
  for (int dt = 0; dt < 8; ++dt) {
    u16x4 v = {f2h(o[dt][0]), f2h(o[dt][1]), f2h(o[dt][2]), f2h(o[dt][3])};
    *(u16x4*)(pb + ((dt * 64 + l) << 2)) = v;
  }
  if (dh == 0 && lr == 0) {
#pragma unroll
    for (int r = 0; r < 4; ++r) {
      float2 v = {M[r], L[r]};
      ml[g * 16384 + b * 2048 + n0 + nw * 16 + lg * 4 + r] = v;
    }
  }
}

// ---------------------------------------------------------------------------
// K2b: merge flash halves -> out0 + lse.  grid 1024 = 256 blin x 4 nw.
// ---------------------------------------------------------------------------
__global__ __launch_bounds__(256) void k_mergeB(const u16* __restrict__ opart,
                                                const float2* __restrict__ ml,
                                                float* __restrict__ out0,
                                                float* __restrict__ lse) {
  __shared__ float4 cf[16];
  const int bid = blockIdx.x;
  const int blin = bid >> 2, nw = bid & 3;
  const int tid = threadIdx.x;
  const int row0 = (blin >> 5) * 2048 + (blin & 31) * 64 + nw * 16;
  if (tid < 16) {
    const float2 m0 = ml[row0 + tid];
    const float2 m1 = ml[16384 + row0 + tid];
    const float Mf = fmaxf(m0.x, m1.x);
    const float c0 = __expf(m0.x - Mf);
    const float c1 = __expf(m1.x - Mf);
    const float Lf = m0.y * c0 + m1.y * c1;
    float4 v = {c0, c1, 1.f / Lf, 0.f};
    cf[tid] = v;
    lse[row0 + tid] = Mf + __logf(Lf);
  }
  __syncthreads();
  const int lane = tid & 63;
#pragma unroll
  for (int k = 0; k < 4; ++k) {
    const int dd = (tid >> 6) * 4 + k;  // 0..15
    const int dh = dd >> 3, dt = dd & 7;
    const size_t c0b = ((size_t)((0 * 256 + blin) * 8 + nw * 2 + dh)) << 11;
    const size_t c1b = ((size_t)((1 * 256 + blin) * 8 + nw * 2 + dh)) << 11;
    const u16x4 v0 = *(const u16x4*)(opart + c0b + ((dt * 64 + lane) << 2));
    const u16x4 v1 = *(const u16x4*)(opart + c1b + ((dt * 64 + lane) << 2));
#pragma unroll
    for (int r = 0; r < 4; ++r) {
      const int i = (lane >> 4) * 4 + r;
      const float4 c = cf[i];
      out0[(size_t)(row0 + i) * DD + dh * 128 + dt * 16 + (lane & 15)] =
          (h2f((u16)v0[r]) * c.x + h2f((u16)v1[r]) * c.y) * c.z;
    }
  }
}

// ---------------------------------------------------------------------------
// K3: transposed pass, same 512-thr structure, gll staging (bQ from qf,
// bT from xb1T with inverse-map source).
// ---------------------------------------------------------------------------
__global__ __launch_bounds__(512, 2) void k_passC(const float* __restrict__ x2f,
                                                  const u16* __restrict__ qf_g,
                                                  const u16* __restrict__ xb1T,
                                                  const float* __restrict__ lse,
                                                  u16* __restrict__ opart) {
  __shared__ char smem[73728];
  const int tid = threadIdx.x;
  const int w = tid >> 6, l = tid & 63, lr = l & 15, lg = l >> 4;
  const int nw = w >> 1, dh = w & 1;
  const int bid = blockIdx.x;
  const int b = bid & 7, mt = (bid >> 3) & 31, g = bid >> 8;
  const int m0 = mt * 64;

  s16x8 xf[8];
  {
    const float* xp = x2f + (size_t)(b * NN + m0 + nw * 16 + lr) * DD;
#pragma unroll
    for (int ks = 0; ks < 8; ++ks) {
      const f32x4 a = *(const f32x4*)(xp + ks * 32 + lg * 8);
      const f32x4 c = *(const f32x4*)(xp + ks * 32 + lg * 8 + 4);
      xf[ks] = cvt8h(a, c);
    }
  }

  const f32x4 zero4 = {0.f, 0.f, 0.f, 0.f};
  f32x4 o[8];
#pragma unroll
  for (int i = 0; i < 8; ++i) o[i] = zero4;

  const u16* qfb = qf_g + (size_t)b * NN * DD;
  const u16* xtb = xb1T + (size_t)b * DD * NN;
  const float* lsb = lse + (size_t)b * NN;
  char* plds = smem + 65536 + w * 1024;

  const int idx0 = w * 2048 + l * 16;
  const int idx1 = idx0 + 1024;
  const int rowN0 = idx0 >> 9, cbN0 = (idx0 & 511) ^ ((rowN0 & 7) << 4);
  const int rowN1 = idx1 >> 9, cbN1 = (idx1 & 511) ^ ((rowN1 & 7) << 4);
  const int da0 = (idx0 >> 6) ^ ((idx0 >> 8) & 1);
  const int sA0 = idx0 ^ ((da0 & 7) << 4);
  const int tRow0 = sA0 >> 6, tCol0 = (sA0 & 63) >> 1;
  const int da1 = (idx1 >> 6) ^ ((idx1 >> 8) & 1);
  const int sA1 = idx1 ^ ((da1 & 7) << 4);
  const int tRow1 = sA1 >> 6, tCol1 = (sA1 & 63) >> 1;

  auto ISSUE = [&](int buf, int nn0) {
    char* bQ = smem + buf * 16384;
    char* bT = smem + 32768 + buf * 16384;
    gll16(qfb + (size_t)(nn0 + rowN0) * DD + (cbN0 >> 1), bQ + w * 2048);
    gll16(qfb + (size_t)(nn0 + rowN1) * DD + (cbN1 >> 1), bQ + w * 2048 + 1024);
    gll16(xtb + (size_t)tRow0 * NN + nn0 + tCol0, bT + w * 2048);
    gll16(xtb + (size_t)tRow1 * NN + nn0 + tCol1, bT + w * 2048 + 1024);
  };

  ISSUE(0, g * 1024);
  __syncthreads();

  for (int t = 0; t < 32; ++t) {
    const int cur = t & 1;
    if (t < 31) ISSUE(cur ^ 1, g * 1024 + (t + 1) * 32);
    const char* bQ = smem + cur * 16384;
    const char* bT = smem + 32768 + cur * 16384;

    // S^T = x2 @ q^T (full, duplicated across the d-pair)
    f32x4 s0 = zero4, s1 = zero4;
#pragma unroll
    for (int ks = 0; ks < 8; ++ks) {
      int off0 = (lr * 512 + ks * 64 + lg * 16) ^ ((lr & 7) << 4);
      const s16x8 b0 = *(const s16x8*)(bQ + off0);
      s0 = MFMA_F16(xf[ks], b0, s0);
      const int n1 = 16 + lr;
      int off1 = (n1 * 512 + ks * 64 + lg * 16) ^ ((n1 & 7) << 4);
      const s16x8 b1 = *(const s16x8*)(bQ + off1);
      s1 = MFMA_F16(xf[ks], b1, s1);
    }

    const int nb = g * 1024 + t * 32;
    const float lv0 = lsb[nb + lr];
    const float lv1 = lsb[nb + 16 + lr];
    float p0[4], p1[4];
#pragma unroll
    for (int r = 0; r < 4; ++r) {
      p0[r] = __expf(s0[r] - lv0);
      p1[r] = __expf(s1[r] - lv1);
    }

#pragma unroll
    for (int r = 0; r < 4; ++r) {
      const int row = lg * 4 + r;
      const int key = (row & 7) << 4;
      int o0 = (row * 64 + lr * 2) ^ key;
      int o1 = (row * 64 + 32 + lr * 2) ^ key;
      *(u16*)(plds + o0) = f2h(p0[r]);
      *(u16*)(plds + o1) = f2h(p1[r]);
    }
    int ra = (lr * 64 + lg * 16) ^ ((lr & 7) << 4);
    const s16x8 pa = *(const s16x8*)(plds + ra);

    // O2 += P^T @ x1 over this wave's d-half
#pragma unroll
    for (int dt = 0; dt < 8; ++dt) {
      const int dl = dh * 128 + dt * 16 + lr;
      int off = (dl * 64 + lg * 16) ^ ((dl & 7) << 4);
      const s16x8 bv = *(const s16x8*)(bT + off);
      o[dt] = MFMA_F16(pa, bv, o[dt]);
    }

    __syncthreads();
  }

  // partial write (additive halves)
  const int blin = b * 32 + mt;
  u16* pb = opart + (((size_t)((g * 256 + blin) * 8 + w)) << 11);
#pragma unroll
  for (int dt = 0; dt < 8; ++dt) {
    u16x4 v = {f2h(o[dt][0]), f2h(o[dt][1]), f2h(o[dt][2]), f2h(o[dt][3])};
    *(u16x4*)(pb + ((dt * 64 + l) << 2)) = v;
  }
}

// ---------------------------------------------------------------------------
// K3b: merge passC halves (pure add) -> out1.
// ---------------------------------------------------------------------------
__global__ __launch_bounds__(256) void k_mergeC(const u16* __restrict__ opart,
                                                float* __restrict__ out1) {
  const int bid = blockIdx.x;
  const int blin = bid >> 2, nw = bid & 3;
  const int tid = threadIdx.x;
  const int row0 = (blin >> 5) * 2048 + (blin & 31) * 64 + nw * 16;
  const int lane = tid & 63;
#pragma unroll
  for (int k = 0; k < 4; ++k) {
    const int dd = (tid >> 6) * 4 + k;
    const int dh = dd >> 3, dt = dd & 7;
    const size_t c0b = ((size_t)((0 * 256 + blin) * 8 + nw * 2 + dh)) << 11;
    const size_t c1b = ((size_t)((1 * 256 + blin) * 8 + nw * 2 + dh)) << 11;
    const u16x4 v0 = *(const u16x4*)(opart + c0b + ((dt * 64 + lane) << 2));
    const u16x4 v1 = *(const u16x4*)(opart + c1b + ((dt * 64 + lane) << 2));
#pragma unroll
    for (int r = 0; r < 4; ++r) {
      const int i = (lane >> 4) * 4 + r;
      out1[(size_t)(row0 + i) * DD + dh * 128 + dt * 16 + (lane & 15)] =
          h2f((u16)v0[r]) + h2f((u16)v1[r]);
    }
  }
}

// ---------------------------------------------------------------------------
extern "C" void kernel_launch(void* const* d_in, const int* in_sizes, int n_in,
                              void* d_out, int out_size, void* d_ws, size_t ws_size,
                              hipStream_t stream) {
  (void)in_sizes; (void)n_in; (void)out_size; (void)ws_size;
  const float* x1 = (const float*)d_in[0];
  const float* x2 = (const float*)d_in[1];
  const float* W  = (const float*)d_in[2];
  const float* bs = (const float*)d_in[3];
  float* out0 = (float*)d_out;
  float* out1 = out0 + (size_t)BB * NN * DD;

  char* ws = (char*)d_ws;
  u16* xb2T  = (u16*)(ws);                  // [B][256][2048] fp16 (8 MB)
  u16* xb1T  = (u16*)(ws + 8388608);        // [B][256][2048] fp16 (8 MB)
  u16* opart = (u16*)(ws + 16777216);       // [2][256][8][2048] fp16 (16 MB)
  // parked in output regions (dead before their final overwrite):
  u16* xb2n   = (u16*)out0;                         // 8.39 MB
  u16* qf     = (u16*)out1;                         // 8.39 MB
  float2* ml  = (float2*)((char*)out1 + 8388608);   // 256 KB
  float* lseb = (float*)((char*)out1 + 8650752);    // 64 KB

  k_conv2<<<dim3(32, 4, 16), 256, 0, stream>>>(x1, x2, xb1T, xb2T, xb2n);
  k_qgemm<<<256, 256, 0, stream>>>(x1, W, bs, qf);
  k_flashB<<<512, 512, 0, stream>>>(qf, xb2n, xb2T, opart, ml);
  k_mergeB<<<1024, 256, 0, stream>>>(opart, ml, out0, lseb);
  k_passC<<<512, 512, 0, stream>>>(x2, qf, xb1T, lseb, opart);
  k_mergeC<<<1024, 256, 0, stream>>>(opart, out1);
}

// Round 18
// 183.470 us; speedup vs baseline: 1.6096x; 1.3422x over previous
//
#include <hip/hip_runtime.h>

#define BB 8
#define NN 2048
#define DD 256

typedef unsigned short u16;
typedef float f32x4 __attribute__((ext_vector_type(4)));
typedef short s16x8 __attribute__((ext_vector_type(8)));
typedef __bf16 bf16x8 __attribute__((ext_vector_type(8)));
typedef _Float16 f16x8 __attribute__((ext_vector_type(8)));
typedef unsigned short u16x4 __attribute__((ext_vector_type(4)));

#define MFMA_BF(a, b, c)                                                       \
  __builtin_amdgcn_mfma_f32_16x16x32_bf16(__builtin_bit_cast(bf16x8, (a)),     \
                                          __builtin_bit_cast(bf16x8, (b)),     \
                                          (c), 0, 0, 0)
#define MFMA_F16(a, b, c)                                                      \
  __builtin_amdgcn_mfma_f32_16x16x32_f16(__builtin_bit_cast(f16x8, (a)),       \
                                         __builtin_bit_cast(f16x8, (b)),       \
                                         (c), 0, 0, 0)

__device__ inline u16 f2bf(float f) {
  union { float f; unsigned u; } v; v.f = f;
  unsigned r = v.u + 0x7FFFu + ((v.u >> 16) & 1u);
  return (u16)(r >> 16);
}
__device__ inline float bf2f(u16 h) {
  union { unsigned u; float f; } v; v.u = ((unsigned)h) << 16;
  return v.f;
}
__device__ inline u16 f2h(float f) {
  _Float16 h = (_Float16)f;
  return __builtin_bit_cast(unsigned short, h);
}
__device__ inline float h2f(u16 h) {
  _Float16 x = __builtin_bit_cast(_Float16, h);
  return (float)x;
}
struct HL { short h, l; };
__device__ inline HL splitbf(float f) {
  HL r;
  u16 hh = f2bf(f);
  r.h = (short)hh;
  r.l = (short)f2bf(f - bf2f(hh));
  return r;
}
__device__ inline void split8(const f32x4 a, const f32x4 c, s16x8& h, s16x8& lo) {
#pragma unroll
  for (int i = 0; i < 4; ++i) {
    HL r = splitbf(a[i]);
    h[i] = r.h; lo[i] = r.l;
  }
#pragma unroll
  for (int i = 0; i < 4; ++i) {
    HL r = splitbf(c[i]);
    h[4 + i] = r.h; lo[4 + i] = r.l;
  }
}
__device__ inline s16x8 cvt8h(const f32x4 a, const f32x4 c) {
  s16x8 h;
#pragma unroll
  for (int i = 0; i < 4; ++i) h[i] = (short)f2h(a[i]);
#pragma unroll
  for (int i = 0; i < 4; ++i) h[4 + i] = (short)f2h(c[i]);
  return h;
}

// async global->LDS, 16B/lane; LDS dest = wave-uniform base + lane*16.
__device__ inline void gll16(const void* g, void* l) {
  __builtin_amdgcn_global_load_lds(
      (const __attribute__((address_space(1))) unsigned int*)g,
      (__attribute__((address_space(3))) unsigned int*)l, 16, 0, 0);
}

// ---------------------------------------------------------------------------
// K0: f32 -> fp16 transposes for x1/x2; x2 also gets a row-major fp16 copy.
// ---------------------------------------------------------------------------
__global__ __launch_bounds__(256) void k_conv2(const float* __restrict__ x1,
                                               const float* __restrict__ x2,
                                               u16* __restrict__ xb1T,
                                               u16* __restrict__ xb2T,
                                               u16* __restrict__ xb2n) {
  __shared__ u16 t[64][68];
  const int zz = blockIdx.z;
  const float* src = (zz < 8) ? x1 : x2;
  u16* dstT = (zz < 8) ? xb1T : xb2T;
  u16* dstN = (zz < 8) ? (u16*)0 : xb2n;
  const int b = zz & 7;
  const int n0 = blockIdx.x * 64;
  const int d0 = blockIdx.y * 64;
  const int tid = threadIdx.x;
  const int r = tid >> 4;
  const int c4 = tid & 15;
#pragma unroll
  for (int rr = 0; rr < 4; ++rr) {
    const int row = r + rr * 16;
    const float4 v = *(const float4*)&src[(size_t)(b * NN + n0 + row) * DD + d0 + c4 * 4];
    u16x4 o2 = {f2h(v.x), f2h(v.y), f2h(v.z), f2h(v.w)};
    if (dstN)
      *(u16x4*)&dstN[(size_t)(b * NN + n0 + row) * DD + d0 + c4 * 4] = o2;
    *(u16x4*)&t[row][c4 * 4] = o2;
  }
  __syncthreads();
  const int d = tid >> 2;
  const int ch = tid & 3;
  u16 buf[16];
#pragma unroll
  for (int j = 0; j < 16; ++j) buf[j] = t[ch * 16 + j][d];
  u16* outp = &dstT[(size_t)(b * DD + d0 + d) * NN + n0 + ch * 16];
  s16x8 v0, v1;
#pragma unroll
  for (int j = 0; j < 8; ++j) { v0[j] = (short)buf[j]; v1[j] = (short)buf[8 + j]; }
  *(s16x8*)outp = v0;
  *(s16x8*)(outp + 8) = v1;
}

// ---------------------------------------------------------------------------
// K1: q = x1 @ W^T + bias via SPLIT-bf16 3-chain (accurate), output fp16.
// ---------------------------------------------------------------------------
__global__ __launch_bounds__(256) void k_qgemm(const float* __restrict__ x1,
                                               const float* __restrict__ W,
                                               const float* __restrict__ bias,
                                               u16* __restrict__ qf) {
  __shared__ char wl[131072];
  const int tid = threadIdx.x;
  const int w = tid >> 6, l = tid & 63, lr = l & 15, lg = l >> 4;
  const int row0 = blockIdx.x * 64 + w * 16;

  s16x8 afh[8], afl[8];
#pragma unroll
  for (int ks = 0; ks < 8; ++ks) {
    const f32x4 a = *(const f32x4*)&x1[(size_t)(row0 + lr) * DD + ks * 32 + lg * 8];
    const f32x4 c = *(const f32x4*)&x1[(size_t)(row0 + lr) * DD + ks * 32 + lg * 8 + 4];
    split8(a, c, afh[ks], afl[ks]);
  }

  const f32x4 zero4 = {0.f, 0.f, 0.f, 0.f};
  f32x4 acc[16];
#pragma unroll
  for (int i = 0; i < 16; ++i) acc[i] = zero4;

  const int er = tid >> 1;
  const int kh = tid & 1;

  for (int eh = 0; eh < 2; ++eh) {
    __syncthreads();
    {
      const int e = eh * 128 + er;
#pragma unroll
      for (int j = 0; j < 16; ++j) {
        const f32x4 a = *(const f32x4*)&W[(size_t)e * DD + kh * 128 + j * 8];
        const f32x4 c = *(const f32x4*)&W[(size_t)e * DD + kh * 128 + j * 8 + 4];
        s16x8 h, lo;
        split8(a, c, h, lo);
        int off = er * 512 + kh * 256 + j * 16;
        off ^= (er & 7) << 4;
        *(s16x8*)(wl + off) = h;
        *(s16x8*)(wl + 65536 + off) = lo;
      }
    }
    __syncthreads();
#pragma unroll
    for (int ct = 0; ct < 8; ++ct) {
      const int el = ct * 16 + lr;
#pragma unroll
      for (int ks = 0; ks < 8; ++ks) {
        int off = el * 512 + ks * 64 + lg * 16;
        off ^= (el & 7) << 4;
        const s16x8 bh = *(const s16x8*)(wl + off);
        const s16x8 bl = *(const s16x8*)(wl + 65536 + off);
        f32x4 acv = acc[eh * 8 + ct];
        acv = MFMA_BF(afh[ks], bh, acv);
        acv = MFMA_BF(afl[ks], bh, acv);
        acv = MFMA_BF(afh[ks], bl, acv);
        acc[eh * 8 + ct] = acv;
      }
    }
  }

#pragma unroll
  for (int i = 0; i < 16; ++i) {
    const int col = (i >> 3) * 128 + (i & 7) * 16 + lr;
    const float bb = bias[col];
#pragma unroll
    for (int r = 0; r < 4; ++r) {
      const int orow = row0 + lg * 4 + r;
      qf[(size_t)orow * DD + col] = f2h(acc[i][r] + bb);
    }
  }
}

// ---------------------------------------------------------------------------
// K2: flash fwd, 256-thr blocks (2/CU), r13 structure + gll staging.
// 4 waves, 16 q-rows each, full d; m in [g*1024,(g+1)*1024), 32 t-steps.
// bN (row-stride 512B): involution source. bT (row-stride 64B): true-inverse
// source (verified in r17). One barrier per t.
// ---------------------------------------------------------------------------
__global__ __launch_bounds__(256, 2) void k_flashB(const u16* __restrict__ qf_g,
                                                   const u16* __restrict__ xb2n,
                                                   const u16* __restrict__ xb2T,
                                                   u16* __restrict__ opart,
                                                   float2* __restrict__ ml) {
  __shared__ char smem[69632];  // 2 bufs x (bN 16K + bT 16K) + plds 4K
  const int tid = threadIdx.x;
  const int w = tid >> 6, l = tid & 63, lr = l & 15, lg = l >> 4;
  const int bid = blockIdx.x;
  const int b = bid & 7, nt = (bid >> 3) & 31, g = bid >> 8;
  const int n0 = nt * 64;

  s16x8 qfr[8];
  {
    const size_t qoff = (size_t)(b * NN + n0 + w * 16 + lr) * DD;
#pragma unroll
    for (int ks = 0; ks < 8; ++ks)
      qfr[ks] = *(const s16x8*)(qf_g + qoff + ks * 32 + lg * 8);
  }

  const f32x4 zero4 = {0.f, 0.f, 0.f, 0.f};
  f32x4 o[16];
#pragma unroll
  for (int i = 0; i < 16; ++i) o[i] = zero4;
  float M[4] = {-INFINITY, -INFINITY, -INFINITY, -INFINITY};
  float L[4] = {0.f, 0.f, 0.f, 0.f};

  const u16* xnb = xb2n + (size_t)b * NN * DD;
  const u16* xtb = xb2T + (size_t)b * DD * NN;
  char* plds = smem + 65536 + w * 1024;

  // per-thread gll source maps: 4 chunks per buffer (j), each 1KB/wave
  const u16* srcN[4];
  const u16* srcT[4];
#pragma unroll
  for (int j = 0; j < 4; ++j) {
    const int idx = j * 4096 + w * 1024 + l * 16;
    const int rowN = idx >> 9;
    const int colN = ((idx & 511) ^ ((rowN & 7) << 4)) >> 1;
    srcN[j] = xnb + (size_t)rowN * DD + colN;       // + (m0)*DD at issue
    const int da = (idx >> 6) ^ ((idx >> 8) & 1);
    const int sA = idx ^ ((da & 7) << 4);
    srcT[j] = xtb + (size_t)(sA >> 6) * NN + ((sA & 63) >> 1);  // + m0
  }

  auto ISSUE = [&](int buf, int m0) {
    char* bN = smem + buf * 32768;
    char* bT = bN + 16384;
#pragma unroll
    for (int j = 0; j < 4; ++j)
      gll16(srcN[j] + (size_t)m0 * DD, bN + j * 4096 + w * 1024);
#pragma unroll
    for (int j = 0; j < 4; ++j)
      gll16(srcT[j] + m0, bT + j * 4096 + w * 1024);
  };

  ISSUE(0, g * 1024);
  __syncthreads();

  for (int t = 0; t < 32; ++t) {
    const int cur = t & 1;
    if (t < 31) ISSUE(cur ^ 1, g * 1024 + (t + 1) * 32);
    const char* bN = smem + cur * 32768;
    const char* bT = bN + 16384;

    // S = q @ x2^T (fp16, 1 chain)
    f32x4 s0 = zero4, s1 = zero4;
#pragma unroll
    for (int ks = 0; ks < 8; ++ks) {
      int off0 = (lr * 512 + ks * 64 + lg * 16) ^ ((lr & 7) << 4);
      const s16x8 b0 = *(const s16x8*)(bN + off0);
      s0 = MFMA_F16(qfr[ks], b0, s0);
      const int m1 = 16 + lr;
      int off1 = (m1 * 512 + ks * 64 + lg * 16) ^ ((m1 & 7) << 4);
      const s16x8 b1 = *(const s16x8*)(bN + off1);
      s1 = MFMA_F16(qfr[ks], b1, s1);
    }

    // online softmax
    float p0[4], p1[4];
#pragma unroll
    for (int r = 0; r < 4; ++r) {
      float tm = fmaxf(s0[r], s1[r]);
      tm = fmaxf(tm, __shfl_xor(tm, 1));
      tm = fmaxf(tm, __shfl_xor(tm, 2));
      tm = fmaxf(tm, __shfl_xor(tm, 4));
      tm = fmaxf(tm, __shfl_xor(tm, 8));
      const float Mn = fmaxf(M[r], tm);
      const float corr = __expf(M[r] - Mn);
      M[r] = Mn;
      p0[r] = __expf(s0[r] - Mn);
      p1[r] = __expf(s1[r] - Mn);
      L[r] = L[r] * corr + p0[r] + p1[r];
#pragma unroll
      for (int dt = 0; dt < 16; ++dt) o[dt][r] *= corr;
    }

    // P relayout (wave-private, (row&7) swizzle), fp16
#pragma unroll
    for (int r = 0; r < 4; ++r) {
      const int row = lg * 4 + r;
      const int key = (row & 7) << 4;
      int o0 = (row * 64 + lr * 2) ^ key;
      int o1 = (row * 64 + 32 + lr * 2) ^ key;
      *(u16*)(plds + o0) = f2h(p0[r]);
      *(u16*)(plds + o1) = f2h(p1[r]);
    }
    int ra = (lr * 64 + lg * 16) ^ ((lr & 7) << 4);
    const s16x8 pa = *(const s16x8*)(plds + ra);

    // O += P @ x2
#pragma unroll
    for (int dt = 0; dt < 16; ++dt) {
      const int dl = dt * 16 + lr;
      int off = (dl * 64 + lg * 16) ^ ((dl & 7) << 4);
      const s16x8 bv = *(const s16x8*)(bT + off);
      o[dt] = MFMA_F16(pa, bv, o[dt]);
    }

    __syncthreads();  // drains gll into next buf + publishes read-done
  }

  // row-sum of L over lr
#pragma unroll
  for (int r = 0; r < 4; ++r) {
    float s = L[r];
    s += __shfl_xor(s, 1); s += __shfl_xor(s, 2);
    s += __shfl_xor(s, 4); s += __shfl_xor(s, 8);
    L[r] = s;
  }

  // partial write: [g][blin][wave][dt][lane][r] fp16
  const int blin = b * 32 + nt;
  u16* pb = opart + (((size_t)(g * 1024 + blin * 4 + w)) << 12);
#pragma unroll
  for (int dt = 0; dt < 16; ++dt) {
    u16x4 v = {f2h(o[dt][0]), f2h(o[dt][1]), f2h(o[dt][2]), f2h(o[dt][3])};
    *(u16x4*)(pb + ((dt * 64 + l) << 2)) = v;
  }
  if (lr == 0) {
#pragma unroll
    for (int r = 0; r < 4; ++r) {
      float2 v = {M[r], L[r]};
      ml[g * 16384 + b * 2048 + n0 + w * 16 + lg * 4 + r] = v;
    }
  }
}

// ---------------------------------------------------------------------------
// K2b: merge flash halves -> out0 + lse.
// ---------------------------------------------------------------------------
__global__ __launch_bounds__(256) void k_mergeB(const u16* __restrict__ opart,
                                                const float2* __restrict__ ml,
                                                float* __restrict__ out0,
                                                float* __restrict__ lse) {
  __shared__ float4 cf[16];
  const int bid = blockIdx.x;  // 1024
  const int blin = bid >> 2, wg = bid & 3;
  const int b = blin >> 5, nt = blin & 31;
  const int tid = threadIdx.x;
  const int row0 = b * 2048 + nt * 64 + wg * 16;
  if (tid < 16) {
    const float2 m0 = ml[row0 + tid];
    const float2 m1 = ml[16384 + row0 + tid];
    const float Mf = fmaxf(m0.x, m1.x);
    const float c0 = __expf(m0.x - Mf);
    const float c1 = __expf(m1.x - Mf);
    const float Lf = m0.y * c0 + m1.y * c1;
    float4 v = {c0, c1, 1.f / Lf, 0.f};
    cf[tid] = v;
    lse[row0 + tid] = Mf + __logf(Lf);
  }
  __syncthreads();
  const int lane = tid & 63;
  const size_t base0 = ((size_t)(blin * 4 + wg)) << 12;
  const size_t base1 = base0 + (1024ull << 12);
#pragma unroll
  for (int k = 0; k < 4; ++k) {
    const int dt = (tid >> 6) * 4 + k;
    const u16x4 v0 = *(const u16x4*)(opart + base0 + ((dt * 64 + lane) << 2));
    const u16x4 v1 = *(const u16x4*)(opart + base1 + ((dt * 64 + lane) << 2));
#pragma unroll
    for (int r = 0; r < 4; ++r) {
      const int i = (lane >> 4) * 4 + r;
      const float4 c = cf[i];
      const float val = (h2f((u16)v0[r]) * c.x + h2f((u16)v1[r]) * c.y) * c.z;
      out0[(size_t)(row0 + i) * DD + dt * 16 + (lane & 15)] = val;
    }
  }
}

// ---------------------------------------------------------------------------
// K3: transposed pass, 256-thr blocks (2/CU), gll staging.
// ---------------------------------------------------------------------------
__global__ __launch_bounds__(256, 2) void k_passC(const float* __restrict__ x2f,
                                                  const u16* __restrict__ qf_g,
                                                  const u16* __restrict__ xb1T,
                                                  const float* __restrict__ lse,
                                                  u16* __restrict__ opart) {
  __shared__ char smem[69632];
  const int tid = threadIdx.x;
  const int w = tid >> 6, l = tid & 63, lr = l & 15, lg = l >> 4;
  const int bid = blockIdx.x;
  const int b = bid & 7, mt = (bid >> 3) & 31, g = bid >> 8;
  const int m0 = mt * 64;

  s16x8 xf[8];
  {
    const float* xp = x2f + (size_t)(b * NN + m0 + w * 16 + lr) * DD;
#pragma unroll
    for (int ks = 0; ks < 8; ++ks) {
      const f32x4 a = *(const f32x4*)(xp + ks * 32 + lg * 8);
      const f32x4 c = *(const f32x4*)(xp + ks * 32 + lg * 8 + 4);
      xf[ks] = cvt8h(a, c);
    }
  }

  const f32x4 zero4 = {0.f, 0.f, 0.f, 0.f};
  f32x4 o[16];
#pragma unroll
  for (int i = 0; i < 16; ++i) o[i] = zero4;

  const u16* qfb = qf_g + (size_t)b * NN * DD;
  const u16* xtb = xb1T + (size_t)b * DD * NN;
  const float* lsb = lse + (size_t)b * NN;
  char* plds = smem + 65536 + w * 1024;

  const u16* srcQ[4];
  const u16* srcT[4];
#pragma unroll
  for (int j = 0; j < 4; ++j) {
    const int idx = j * 4096 + w * 1024 + l * 16;
    const int rowN = idx >> 9;
    const int colN = ((idx & 511) ^ ((rowN & 7) << 4)) >> 1;
    srcQ[j] = qfb + (size_t)rowN * DD + colN;
    const int da = (idx >> 6) ^ ((idx >> 8) & 1);
    const int sA = idx ^ ((da & 7) << 4);
    srcT[j] = xtb + (size_t)(sA >> 6) * NN + ((sA & 63) >> 1);
  }

  auto ISSUE = [&](int buf, int nn0) {
    char* bQ = smem + buf * 32768;
    char* bT = bQ + 16384;
#pragma unroll
    for (int j = 0; j < 4; ++j)
      gll16(srcQ[j] + (size_t)nn0 * DD, bQ + j * 4096 + w * 1024);
#pragma unroll
    for (int j = 0; j < 4; ++j)
      gll16(srcT[j] + nn0, bT + j * 4096 + w * 1024);
  };

  ISSUE(0, g * 1024);
  __syncthreads();

  for (int t = 0; t < 32; ++t) {
    const int cur = t & 1;
    if (t < 31) ISSUE(cur ^ 1, g * 1024 + (t + 1) * 32);
    const char* bQ = smem + cur * 32768;
    const char* bT = bQ + 16384;

    // S^T = x2 @ q^T (fp16, 1 chain)
    f32x4 s0 = zero4, s1 = zero4;
#pragma unroll
    for (int ks = 0; ks < 8; ++ks) {
      int off0 = (lr * 512 + ks * 64 + lg * 16) ^ ((lr & 7) << 4);
      const s16x8 b0 = *(const s16x8*)(bQ + off0);
      s0 = MFMA_F16(xf[ks], b0, s0);
      const int n1 = 16 + lr;
      int off1 = (n1 * 512 + ks * 64 + lg * 16) ^ ((n1 & 7) << 4);
      const s16x8 b1 = *(const s16x8*)(bQ + off1);
      s1 = MFMA_F16(xf[ks], b1, s1);
    }

    const int nb = g * 1024 + t * 32;
    const float lv0 = lsb[nb + lr];
    const float lv1 = lsb[nb + 16 + lr];
    float p0[4], p1[4];
#pragma unroll
    for (int r = 0; r < 4; ++r) {
      p0[r] = __expf(s0[r] - lv0);
      p1[r] = __expf(s1[r] - lv1);
    }

#pragma unroll
    for (int r = 0; r < 4; ++r) {
      const int row = lg * 4 + r;
      const int key = (row & 7) << 4;
      int o0 = (row * 64 + lr * 2) ^ key;
      int o1 = (row * 64 + 32 + lr * 2) ^ key;
      *(u16*)(plds + o0) = f2h(p0[r]);
      *(u16*)(plds + o1) = f2h(p1[r]);
    }
    int ra = (lr * 64 + lg * 16) ^ ((lr & 7) << 4);
    const s16x8 pa = *(const s16x8*)(plds + ra);

    // O2 += P^T @ x1
#pragma unroll
    for (int dt = 0; dt < 16; ++dt) {
      const int dl = dt * 16 + lr;
      int off = (dl * 64 + lg * 16) ^ ((dl & 7) << 4);
      const s16x8 bv = *(const s16x8*)(bT + off);
      o[dt] = MFMA_F16(pa, bv, o[dt]);
    }

    __syncthreads();
  }

  // partial write (fragment layout fp16)
  const int blin = b * 32 + mt;
  u16* pb = opart + (((size_t)(g * 1024 + blin * 4 + w)) << 12);
#pragma unroll
  for (int dt = 0; dt < 16; ++dt) {
    u16x4 v = {f2h(o[dt][0]), f2h(o[dt][1]), f2h(o[dt][2]), f2h(o[dt][3])};
    *(u16x4*)(pb + ((dt * 64 + l) << 2)) = v;
  }
}

// ---------------------------------------------------------------------------
// K3b: merge passC halves (pure add) -> out1.
// ---------------------------------------------------------------------------
__global__ __launch_bounds__(256) void k_mergeC(const u16* __restrict__ opart,
                                                float* __restrict__ out1) {
  const int bid = blockIdx.x;  // 1024
  const int blin = bid >> 2, wg = bid & 3;
  const int b = blin >> 5, mt = blin & 31;
  const int tid = threadIdx.x;
  const int row0 = b * 2048 + mt * 64 + wg * 16;
  const int lane = tid & 63;
  const size_t base0 = ((size_t)(blin * 4 + wg)) << 12;
  const size_t base1 = base0 + (1024ull << 12);
#pragma unroll
  for (int k = 0; k < 4; ++k) {
    const int dt = (tid >> 6) * 4 + k;
    const u16x4 v0 = *(const u16x4*)(opart + base0 + ((dt * 64 + lane) << 2));
    const u16x4 v1 = *(const u16x4*)(opart + base1 + ((dt * 64 + lane) << 2));
#pragma unroll
    for (int r = 0; r < 4; ++r) {
      const int i = (lane >> 4) * 4 + r;
      out1[(size_t)(row0 + i) * DD + dt * 16 + (lane & 15)] =
          h2f((u16)v0[r]) + h2f((u16)v1[r]);
    }
  }
}

// ---------------------------------------------------------------------------
extern "C" void kernel_launch(void* const* d_in, const int* in_sizes, int n_in,
                              void* d_out, int out_size, void* d_ws, size_t ws_size,
                              hipStream_t stream) {
  (void)in_sizes; (void)n_in; (void)out_size; (void)ws_size;
  const float* x1 = (const float*)d_in[0];
  const float* x2 = (const float*)d_in[1];
  const float* W  = (const float*)d_in[2];
  const float* bs = (const float*)d_in[3];
  float* out0 = (float*)d_out;
  float* out1 = out0 + (size_t)BB * NN * DD;

  char* ws = (char*)d_ws;
  u16* xb2T  = (u16*)(ws);                  // [B][256][2048] fp16 (8 MB)
  u16* xb1T  = (u16*)(ws + 8388608);        // [B][256][2048] fp16 (8 MB)
  u16* opart = (u16*)(ws + 16777216);       // [2][1024][4096] fp16 (16 MB)
  // parked in output regions (dead before their final overwrite):
  u16* xb2n   = (u16*)out0;                         // 8.39 MB
  u16* qf     = (u16*)out1;                         // 8.39 MB
  float2* ml  = (float2*)((char*)out1 + 8388608);   // 256 KB
  float* lseb = (float*)((char*)out1 + 8650752);    // 64 KB

  k_conv2<<<dim3(32, 4, 16), 256, 0, stream>>>(x1, x2, xb1T, xb2T, xb2n);
  k_qgemm<<<256, 256, 0, stream>>>(x1, W, bs, qf);
  k_flashB<<<512, 256, 0, stream>>>(qf, xb2n, xb2T, opart, ml);
  k_mergeB<<<1024, 256, 0, stream>>>(opart, ml, out0, lseb);
  k_passC<<<512, 256, 0, stream>>>(x2, qf, xb1T, lseb, opart);
  k_mergeC<<<1024, 256, 0, stream>>>(opart, out1);
}

// Round 19
// 181.486 us; speedup vs baseline: 1.6272x; 1.0109x over previous
//
#include <hip/hip_runtime.h>

#define BB 8
#define NN 2048
#define DD 256

typedef unsigned short u16;
typedef float f32x4 __attribute__((ext_vector_type(4)));
typedef short s16x8 __attribute__((ext_vector_type(8)));
typedef __bf16 bf16x8 __attribute__((ext_vector_type(8)));
typedef _Float16 f16x8 __attribute__((ext_vector_type(8)));
typedef unsigned short u16x4 __attribute__((ext_vector_type(4)));

#define MFMA_BF(a, b, c)                                                       \
  __builtin_amdgcn_mfma_f32_16x16x32_bf16(__builtin_bit_cast(bf16x8, (a)),     \
                                          __builtin_bit_cast(bf16x8, (b)),     \
                                          (c), 0, 0, 0)
#define MFMA_F16(a, b, c)                                                      \
  __builtin_amdgcn_mfma_f32_16x16x32_f16(__builtin_bit_cast(f16x8, (a)),       \
                                         __builtin_bit_cast(f16x8, (b)),       \
                                         (c), 0, 0, 0)

__device__ inline u16 f2bf(float f) {
  union { float f; unsigned u; } v; v.f = f;
  unsigned r = v.u + 0x7FFFu + ((v.u >> 16) & 1u);
  return (u16)(r >> 16);
}
__device__ inline float bf2f(u16 h) {
  union { unsigned u; float f; } v; v.u = ((unsigned)h) << 16;
  return v.f;
}
__device__ inline u16 f2h(float f) {
  _Float16 h = (_Float16)f;
  return __builtin_bit_cast(unsigned short, h);
}
__device__ inline float h2f(u16 h) {
  _Float16 x = __builtin_bit_cast(_Float16, h);
  return (float)x;
}
struct HL { short h, l; };
__device__ inline HL splitbf(float f) {
  HL r;
  u16 hh = f2bf(f);
  r.h = (short)hh;
  r.l = (short)f2bf(f - bf2f(hh));
  return r;
}
__device__ inline void split8(const f32x4 a, const f32x4 c, s16x8& h, s16x8& lo) {
#pragma unroll
  for (int i = 0; i < 4; ++i) {
    HL r = splitbf(a[i]);
    h[i] = r.h; lo[i] = r.l;
  }
#pragma unroll
  for (int i = 0; i < 4; ++i) {
    HL r = splitbf(c[i]);
    h[4 + i] = r.h; lo[4 + i] = r.l;
  }
}
__device__ inline s16x8 cvt8h(const f32x4 a, const f32x4 c) {
  s16x8 h;
#pragma unroll
  for (int i = 0; i < 4; ++i) h[i] = (short)f2h(a[i]);
#pragma unroll
  for (int i = 0; i < 4; ++i) h[4 + i] = (short)f2h(c[i]);
  return h;
}

// async global->LDS, 16B/lane; LDS dest = wave-uniform base + lane*16.
__device__ inline void gll16(const void* g, void* l) {
  __builtin_amdgcn_global_load_lds(
      (const __attribute__((address_space(1))) unsigned int*)g,
      (__attribute__((address_space(3))) unsigned int*)l, 16, 0, 0);
}

// ---------------------------------------------------------------------------
// K0: f32 -> fp16 transposes for x1/x2; x2 also gets a row-major fp16 copy.
// ---------------------------------------------------------------------------
__global__ __launch_bounds__(256) void k_conv2(const float* __restrict__ x1,
                                               const float* __restrict__ x2,
                                               u16* __restrict__ xb1T,
                                               u16* __restrict__ xb2T,
                                               u16* __restrict__ xb2n) {
  __shared__ u16 t[64][68];
  const int zz = blockIdx.z;
  const float* src = (zz < 8) ? x1 : x2;
  u16* dstT = (zz < 8) ? xb1T : xb2T;
  u16* dstN = (zz < 8) ? (u16*)0 : xb2n;
  const int b = zz & 7;
  const int n0 = blockIdx.x * 64;
  const int d0 = blockIdx.y * 64;
  const int tid = threadIdx.x;
  const int r = tid >> 4;
  const int c4 = tid & 15;
#pragma unroll
  for (int rr = 0; rr < 4; ++rr) {
    const int row = r + rr * 16;
    const float4 v = *(const float4*)&src[(size_t)(b * NN + n0 + row) * DD + d0 + c4 * 4];
    u16x4 o2 = {f2h(v.x), f2h(v.y), f2h(v.z), f2h(v.w)};
    if (dstN)
      *(u16x4*)&dstN[(size_t)(b * NN + n0 + row) * DD + d0 + c4 * 4] = o2;
    *(u16x4*)&t[row][c4 * 4] = o2;
  }
  __syncthreads();
  const int d = tid >> 2;
  const int ch = tid & 3;
  u16 buf[16];
#pragma unroll
  for (int j = 0; j < 16; ++j) buf[j] = t[ch * 16 + j][d];
  u16* outp = &dstT[(size_t)(b * DD + d0 + d) * NN + n0 + ch * 16];
  s16x8 v0, v1;
#pragma unroll
  for (int j = 0; j < 8; ++j) { v0[j] = (short)buf[j]; v1[j] = (short)buf[8 + j]; }
  *(s16x8*)outp = v0;
  *(s16x8*)(outp + 8) = v1;
}

// ---------------------------------------------------------------------------
// K1: q = x1 @ W^T + bias via SPLIT-bf16 3-chain (accurate), output fp16.
// ---------------------------------------------------------------------------
__global__ __launch_bounds__(256) void k_qgemm(const float* __restrict__ x1,
                                               const float* __restrict__ W,
                                               const float* __restrict__ bias,
                                               u16* __restrict__ qf) {
  __shared__ char wl[131072];
  const int tid = threadIdx.x;
  const int w = tid >> 6, l = tid & 63, lr = l & 15, lg = l >> 4;
  const int row0 = blockIdx.x * 64 + w * 16;

  s16x8 afh[8], afl[8];
#pragma unroll
  for (int ks = 0; ks < 8; ++ks) {
    const f32x4 a = *(const f32x4*)&x1[(size_t)(row0 + lr) * DD + ks * 32 + lg * 8];
    const f32x4 c = *(const f32x4*)&x1[(size_t)(row0 + lr) * DD + ks * 32 + lg * 8 + 4];
    split8(a, c, afh[ks], afl[ks]);
  }

  const f32x4 zero4 = {0.f, 0.f, 0.f, 0.f};
  f32x4 acc[16];
#pragma unroll
  for (int i = 0; i < 16; ++i) acc[i] = zero4;

  const int er = tid >> 1;
  const int kh = tid & 1;

  for (int eh = 0; eh < 2; ++eh) {
    __syncthreads();
    {
      const int e = eh * 128 + er;
#pragma unroll
      for (int j = 0; j < 16; ++j) {
        const f32x4 a = *(const f32x4*)&W[(size_t)e * DD + kh * 128 + j * 8];
        const f32x4 c = *(const f32x4*)&W[(size_t)e * DD + kh * 128 + j * 8 + 4];
        s16x8 h, lo;
        split8(a, c, h, lo);
        int off = er * 512 + kh * 256 + j * 16;
        off ^= (er & 7) << 4;
        *(s16x8*)(wl + off) = h;
        *(s16x8*)(wl + 65536 + off) = lo;
      }
    }
    __syncthreads();
#pragma unroll
    for (int ct = 0; ct < 8; ++ct) {
      const int el = ct * 16 + lr;
#pragma unroll
      for (int ks = 0; ks < 8; ++ks) {
        int off = el * 512 + ks * 64 + lg * 16;
        off ^= (el & 7) << 4;
        const s16x8 bh = *(const s16x8*)(wl + off);
        const s16x8 bl = *(const s16x8*)(wl + 65536 + off);
        f32x4 acv = acc[eh * 8 + ct];
        acv = MFMA_BF(afh[ks], bh, acv);
        acv = MFMA_BF(afl[ks], bh, acv);
        acv = MFMA_BF(afh[ks], bl, acv);
        acc[eh * 8 + ct] = acv;
      }
    }
  }

#pragma unroll
  for (int i = 0; i < 16; ++i) {
    const int col = (i >> 3) * 128 + (i & 7) * 16 + lr;
    const float bb = bias[col];
#pragma unroll
    for (int r = 0; r < 4; ++r) {
      const int orow = row0 + lg * 4 + r;
      qf[(size_t)orow * DD + col] = f2h(acc[i][r] + bb);
    }
  }
}

// ---------------------------------------------------------------------------
// K2: flash fwd, 256-thr blocks (2/CU), gll staging + T5 setprio around
// MFMA clusters. 4 waves, 16 q-rows each, full d; 32 t-steps, dbuf,
// one barrier per t.
// ---------------------------------------------------------------------------
__global__ __launch_bounds__(256, 2) void k_flashB(const u16* __restrict__ qf_g,
                                                   const u16* __restrict__ xb2n,
                                                   const u16* __restrict__ xb2T,
                                                   u16* __restrict__ opart,
                                                   float2* __restrict__ ml) {
  __shared__ char smem[69632];  // 2 bufs x (bN 16K + bT 16K) + plds 4K
  const int tid = threadIdx.x;
  const int w = tid >> 6, l = tid & 63, lr = l & 15, lg = l >> 4;
  const int bid = blockIdx.x;
  const int b = bid & 7, nt = (bid >> 3) & 31, g = bid >> 8;
  const int n0 = nt * 64;

  s16x8 qfr[8];
  {
    const size_t qoff = (size_t)(b * NN + n0 + w * 16 + lr) * DD;
#pragma unroll
    for (int ks = 0; ks < 8; ++ks)
      qfr[ks] = *(const s16x8*)(qf_g + qoff + ks * 32 + lg * 8);
  }

  const f32x4 zero4 = {0.f, 0.f, 0.f, 0.f};
  f32x4 o[16];
#pragma unroll
  for (int i = 0; i < 16; ++i) o[i] = zero4;
  float M[4] = {-INFINITY, -INFINITY, -INFINITY, -INFINITY};
  float L[4] = {0.f, 0.f, 0.f, 0.f};

  const u16* xnb = xb2n + (size_t)b * NN * DD;
  const u16* xtb = xb2T + (size_t)b * DD * NN;
  char* plds = smem + 65536 + w * 1024;

  // per-thread gll source maps: 4 chunks per buffer (j), each 1KB/wave
  const u16* srcN[4];
  const u16* srcT[4];
#pragma unroll
  for (int j = 0; j < 4; ++j) {
    const int idx = j * 4096 + w * 1024 + l * 16;
    const int rowN = idx >> 9;
    const int colN = ((idx & 511) ^ ((rowN & 7) << 4)) >> 1;
    srcN[j] = xnb + (size_t)rowN * DD + colN;       // + (m0)*DD at issue
    const int da = (idx >> 6) ^ ((idx >> 8) & 1);
    const int sA = idx ^ ((da & 7) << 4);
    srcT[j] = xtb + (size_t)(sA >> 6) * NN + ((sA & 63) >> 1);  // + m0
  }

  auto ISSUE = [&](int buf, int m0) {
    char* bN = smem + buf * 32768;
    char* bT = bN + 16384;
#pragma unroll
    for (int j = 0; j < 4; ++j)
      gll16(srcN[j] + (size_t)m0 * DD, bN + j * 4096 + w * 1024);
#pragma unroll
    for (int j = 0; j < 4; ++j)
      gll16(srcT[j] + m0, bT + j * 4096 + w * 1024);
  };

  ISSUE(0, g * 1024);
  __syncthreads();

  for (int t = 0; t < 32; ++t) {
    const int cur = t & 1;
    if (t < 31) ISSUE(cur ^ 1, g * 1024 + (t + 1) * 32);
    const char* bN = smem + cur * 32768;
    const char* bT = bN + 16384;

    // S = q @ x2^T (fp16, 1 chain)  [T5: boost MFMA cluster]
    __builtin_amdgcn_s_setprio(1);
    f32x4 s0 = zero4, s1 = zero4;
#pragma unroll
    for (int ks = 0; ks < 8; ++ks) {
      int off0 = (lr * 512 + ks * 64 + lg * 16) ^ ((lr & 7) << 4);
      const s16x8 b0 = *(const s16x8*)(bN + off0);
      s0 = MFMA_F16(qfr[ks], b0, s0);
      const int m1 = 16 + lr;
      int off1 = (m1 * 512 + ks * 64 + lg * 16) ^ ((m1 & 7) << 4);
      const s16x8 b1 = *(const s16x8*)(bN + off1);
      s1 = MFMA_F16(qfr[ks], b1, s1);
    }
    __builtin_amdgcn_s_setprio(0);

    // online softmax
    float p0[4], p1[4];
#pragma unroll
    for (int r = 0; r < 4; ++r) {
      float tm = fmaxf(s0[r], s1[r]);
      tm = fmaxf(tm, __shfl_xor(tm, 1));
      tm = fmaxf(tm, __shfl_xor(tm, 2));
      tm = fmaxf(tm, __shfl_xor(tm, 4));
      tm = fmaxf(tm, __shfl_xor(tm, 8));
      const float Mn = fmaxf(M[r], tm);
      const float corr = __expf(M[r] - Mn);
      M[r] = Mn;
      p0[r] = __expf(s0[r] - Mn);
      p1[r] = __expf(s1[r] - Mn);
      L[r] = L[r] * corr + p0[r] + p1[r];
#pragma unroll
      for (int dt = 0; dt < 16; ++dt) o[dt][r] *= corr;
    }

    // P relayout (wave-private, (row&7) swizzle), fp16
#pragma unroll
    for (int r = 0; r < 4; ++r) {
      const int row = lg * 4 + r;
      const int key = (row & 7) << 4;
      int o0 = (row * 64 + lr * 2) ^ key;
      int o1 = (row * 64 + 32 + lr * 2) ^ key;
      *(u16*)(plds + o0) = f2h(p0[r]);
      *(u16*)(plds + o1) = f2h(p1[r]);
    }
    int ra = (lr * 64 + lg * 16) ^ ((lr & 7) << 4);
    const s16x8 pa = *(const s16x8*)(plds + ra);

    // O += P @ x2  [T5: boost MFMA cluster]
    __builtin_amdgcn_s_setprio(1);
#pragma unroll
    for (int dt = 0; dt < 16; ++dt) {
      const int dl = dt * 16 + lr;
      int off = (dl * 64 + lg * 16) ^ ((dl & 7) << 4);
      const s16x8 bv = *(const s16x8*)(bT + off);
      o[dt] = MFMA_F16(pa, bv, o[dt]);
    }
    __builtin_amdgcn_s_setprio(0);

    __syncthreads();  // drains gll into next buf + publishes read-done
  }

  // row-sum of L over lr
#pragma unroll
  for (int r = 0; r < 4; ++r) {
    float s = L[r];
    s += __shfl_xor(s, 1); s += __shfl_xor(s, 2);
    s += __shfl_xor(s, 4); s += __shfl_xor(s, 8);
    L[r] = s;
  }

  // partial write: [g][blin][wave][dt][lane][r] fp16
  const int blin = b * 32 + nt;
  u16* pb = opart + (((size_t)(g * 1024 + blin * 4 + w)) << 12);
#pragma unroll
  for (int dt = 0; dt < 16; ++dt) {
    u16x4 v = {f2h(o[dt][0]), f2h(o[dt][1]), f2h(o[dt][2]), f2h(o[dt][3])};
    *(u16x4*)(pb + ((dt * 64 + l) << 2)) = v;
  }
  if (lr == 0) {
#pragma unroll
    for (int r = 0; r < 4; ++r) {
      float2 v = {M[r], L[r]};
      ml[g * 16384 + b * 2048 + n0 + w * 16 + lg * 4 + r] = v;
    }
  }
}

// ---------------------------------------------------------------------------
// K2b: merge flash halves -> out0 + lse.
// ---------------------------------------------------------------------------
__global__ __launch_bounds__(256) void k_mergeB(const u16* __restrict__ opart,
                                                const float2* __restrict__ ml,
                                                float* __restrict__ out0,
                                                float* __restrict__ lse) {
  __shared__ float4 cf[16];
  const int bid = blockIdx.x;  // 1024
  const int blin = bid >> 2, wg = bid & 3;
  const int b = blin >> 5, nt = blin & 31;
  const int tid = threadIdx.x;
  const int row0 = b * 2048 + nt * 64 + wg * 16;
  if (tid < 16) {
    const float2 m0 = ml[row0 + tid];
    const float2 m1 = ml[16384 + row0 + tid];
    const float Mf = fmaxf(m0.x, m1.x);
    const float c0 = __expf(m0.x - Mf);
    const float c1 = __expf(m1.x - Mf);
    const float Lf = m0.y * c0 + m1.y * c1;
    float4 v = {c0, c1, 1.f / Lf, 0.f};
    cf[tid] = v;
    lse[row0 + tid] = Mf + __logf(Lf);
  }
  __syncthreads();
  const int lane = tid & 63;
  const size_t base0 = ((size_t)(blin * 4 + wg)) << 12;
  const size_t base1 = base0 + (1024ull << 12);
#pragma unroll
  for (int k = 0; k < 4; ++k) {
    const int dt = (tid >> 6) * 4 + k;
    const u16x4 v0 = *(const u16x4*)(opart + base0 + ((dt * 64 + lane) << 2));
    const u16x4 v1 = *(const u16x4*)(opart + base1 + ((dt * 64 + lane) << 2));
#pragma unroll
    for (int r = 0; r < 4; ++r) {
      const int i = (lane >> 4) * 4 + r;
      const float4 c = cf[i];
      const float val = (h2f((u16)v0[r]) * c.x + h2f((u16)v1[r]) * c.y) * c.z;
      out0[(size_t)(row0 + i) * DD + dt * 16 + (lane & 15)] = val;
    }
  }
}

// ---------------------------------------------------------------------------
// K3: transposed pass, 256-thr blocks (2/CU), gll staging + T5 setprio.
// ---------------------------------------------------------------------------
__global__ __launch_bounds__(256, 2) void k_passC(const float* __restrict__ x2f,
                                                  const u16* __restrict__ qf_g,
                                                  const u16* __restrict__ xb1T,
                                                  const float* __restrict__ lse,
                                                  u16* __restrict__ opart) {
  __shared__ char smem[69632];
  const int tid = threadIdx.x;
  const int w = tid >> 6, l = tid & 63, lr = l & 15, lg = l >> 4;
  const int bid = blockIdx.x;
  const int b = bid & 7, mt = (bid >> 3) & 31, g = bid >> 8;
  const int m0 = mt * 64;

  s16x8 xf[8];
  {
    const float* xp = x2f + (size_t)(b * NN + m0 + w * 16 + lr) * DD;
#pragma unroll
    for (int ks = 0; ks < 8; ++ks) {
      const f32x4 a = *(const f32x4*)(xp + ks * 32 + lg * 8);
      const f32x4 c = *(const f32x4*)(xp + ks * 32 + lg * 8 + 4);
      xf[ks] = cvt8h(a, c);
    }
  }

  const f32x4 zero4 = {0.f, 0.f, 0.f, 0.f};
  f32x4 o[16];
#pragma unroll
  for (int i = 0; i < 16; ++i) o[i] = zero4;

  const u16* qfb = qf_g + (size_t)b * NN * DD;
  const u16* xtb = xb1T + (size_t)b * DD * NN;
  const float* lsb = lse + (size_t)b * NN;
  char* plds = smem + 65536 + w * 1024;

  const u16* srcQ[4];
  const u16* srcT[4];
#pragma unroll
  for (int j = 0; j < 4; ++j) {
    const int idx = j * 4096 + w * 1024 + l * 16;
    const int rowN = idx >> 9;
    const int colN = ((idx & 511) ^ ((rowN & 7) << 4)) >> 1;
    srcQ[j] = qfb + (size_t)rowN * DD + colN;
    const int da = (idx >> 6) ^ ((idx >> 8) & 1);
    const int sA = idx ^ ((da & 7) << 4);
    srcT[j] = xtb + (size_t)(sA >> 6) * NN + ((sA & 63) >> 1);
  }

  auto ISSUE = [&](int buf, int nn0) {
    char* bQ = smem + buf * 32768;
    char* bT = bQ + 16384;
#pragma unroll
    for (int j = 0; j < 4; ++j)
      gll16(srcQ[j] + (size_t)nn0 * DD, bQ + j * 4096 + w * 1024);
#pragma unroll
    for (int j = 0; j < 4; ++j)
      gll16(srcT[j] + nn0, bT + j * 4096 + w * 1024);
  };

  ISSUE(0, g * 1024);
  __syncthreads();

  for (int t = 0; t < 32; ++t) {
    const int cur = t & 1;
    if (t < 31) ISSUE(cur ^ 1, g * 1024 + (t + 1) * 32);
    const char* bQ = smem + cur * 32768;
    const char* bT = bQ + 16384;

    // S^T = x2 @ q^T (fp16, 1 chain)  [T5]
    __builtin_amdgcn_s_setprio(1);
    f32x4 s0 = zero4, s1 = zero4;
#pragma unroll
    for (int ks = 0; ks < 8; ++ks) {
      int off0 = (lr * 512 + ks * 64 + lg * 16) ^ ((lr & 7) << 4);
      const s16x8 b0 = *(const s16x8*)(bQ + off0);
      s0 = MFMA_F16(xf[ks], b0, s0);
      const int n1 = 16 + lr;
      int off1 = (n1 * 512 + ks * 64 + lg * 16) ^ ((n1 & 7) << 4);
      const s16x8 b1 = *(const s16x8*)(bQ + off1);
      s1 = MFMA_F16(xf[ks], b1, s1);
    }
    __builtin_amdgcn_s_setprio(0);

    const int nb = g * 1024 + t * 32;
    const float lv0 = lsb[nb + lr];
    const float lv1 = lsb[nb + 16 + lr];
    float p0[4], p1[4];
#pragma unroll
    for (int r = 0; r < 4; ++r) {
      p0[r] = __expf(s0[r] - lv0);
      p1[r] = __expf(s1[r] - lv1);
    }

#pragma unroll
    for (int r = 0; r < 4; ++r) {
      const int row = lg * 4 + r;
      const int key = (row & 7) << 4;
      int o0 = (row * 64 + lr * 2) ^ key;
      int o1 = (row * 64 + 32 + lr * 2) ^ key;
      *(u16*)(plds + o0) = f2h(p0[r]);
      *(u16*)(plds + o1) = f2h(p1[r]);
    }
    int ra = (lr * 64 + lg * 16) ^ ((lr & 7) << 4);
    const s16x8 pa = *(const s16x8*)(plds + ra);

    // O2 += P^T @ x1  [T5]
    __builtin_amdgcn_s_setprio(1);
#pragma unroll
    for (int dt = 0; dt < 16; ++dt) {
      const int dl = dt * 16 + lr;
      int off = (dl * 64 + lg * 16) ^ ((dl & 7) << 4);
      const s16x8 bv = *(const s16x8*)(bT + off);
      o[dt] = MFMA_F16(pa, bv, o[dt]);
    }
    __builtin_amdgcn_s_setprio(0);

    __syncthreads();
  }

  // partial write (fragment layout fp16)
  const int blin = b * 32 + mt;
  u16* pb = opart + (((size_t)(g * 1024 + blin * 4 + w)) << 12);
#pragma unroll
  for (int dt = 0; dt < 16; ++dt) {
    u16x4 v = {f2h(o[dt][0]), f2h(o[dt][1]), f2h(o[dt][2]), f2h(o[dt][3])};
    *(u16x4*)(pb + ((dt * 64 + l) << 2)) = v;
  }
}

// ---------------------------------------------------------------------------
// K3b: merge passC halves (pure add) -> out1.
// ---------------------------------------------------------------------------
__global__ __launch_bounds__(256) void k_mergeC(const u16* __restrict__ opart,
                                                float* __restrict__ out1) {
  const int bid = blockIdx.x;  // 1024
  const int blin = bid >> 2, wg = bid & 3;
  const int b = blin >> 5, mt = blin & 31;
  const int tid = threadIdx.x;
  const int row0 = b * 2048 + mt * 64 + wg * 16;
  const int lane = tid & 63;
  const size_t base0 = ((size_t)(blin * 4 + wg)) << 12;
  const size_t base1 = base0 + (1024ull << 12);
#pragma unroll
  for (int k = 0; k < 4; ++k) {
    const int dt = (tid >> 6) * 4 + k;
    const u16x4 v0 = *(const u16x4*)(opart + base0 + ((dt * 64 + lane) << 2));
    const u16x4 v1 = *(const u16x4*)(opart + base1 + ((dt * 64 + lane) << 2));
#pragma unroll
    for (int r = 0; r < 4; ++r) {
      const int i = (lane >> 4) * 4 + r;
      out1[(size_t)(row0 + i) * DD + dt * 16 + (lane & 15)] =
          h2f((u16)v0[r]) + h2f((u16)v1[r]);
    }
  }
}

// ---------------------------------------------------------------------------
extern "C" void kernel_launch(void* const* d_in, const int* in_sizes, int n_in,
                              void* d_out, int out_size, void* d_ws, size_t ws_size,
                              hipStream_t stream) {
  (void)in_sizes; (void)n_in; (void)out_size; (void)ws_size;
  const float* x1 = (const float*)d_in[0];
  const float* x2 = (const float*)d_in[1];
  const float* W  = (const float*)d_in[2];
  const float* bs = (const float*)d_in[3];
  float* out0 = (float*)d_out;
  float* out1 = out0 + (size_t)BB * NN * DD;

  char* ws = (char*)d_ws;
  u16* xb2T  = (u16*)(ws);                  // [B][256][2048] fp16 (8 MB)
  u16* xb1T  = (u16*)(ws + 8388608);        // [B][256][2048] fp16 (8 MB)
  u16* opart = (u16*)(ws + 16777216);       // [2][1024][4096] fp16 (16 MB)
  // parked in output regions (dead before their final overwrite):
  u16* xb2n   = (u16*)out0;                         // 8.39 MB
  u16* qf     = (u16*)out1;                         // 8.39 MB
  float2* ml  = (float2*)((char*)out1 + 8388608);   // 256 KB
  float* lseb = (float*)((char*)out1 + 8650752);    // 64 KB

  k_conv2<<<dim3(32, 4, 16), 256, 0, stream>>>(x1, x2, xb1T, xb2T, xb2n);
  k_qgemm<<<256, 256, 0, stream>>>(x1, W, bs, qf);
  k_flashB<<<512, 256, 0, stream>>>(qf, xb2n, xb2T, opart, ml);
  k_mergeB<<<1024, 256, 0, stream>>>(opart, ml, out0, lseb);
  k_passC<<<512, 256, 0, stream>>>(x2, qf, xb1T, lseb, opart);
  k_mergeC<<<1024, 256, 0, stream>>>(opart, out1);
}